// Round 17
// baseline (1115.020 us; speedup 1.0000x reference)
//
#include <hip/hip_runtime.h>
#include <math.h>

#define B_TOT 4096
#define CHUNK 4096

typedef _Float16 half_t;
typedef _Float16 h2 __attribute__((ext_vector_type(2)));
typedef _Float16 h8v __attribute__((ext_vector_type(8)));
typedef float f4v __attribute__((ext_vector_type(4)));
typedef float f2v __attribute__((ext_vector_type(2)));

#if __has_builtin(__builtin_amdgcn_fdot2)
#define FDOT2(a, b, c) __builtin_amdgcn_fdot2((a), (b), (c), false)
#else
#define FDOT2(a, b, c) fmaf((float)(a)[1], (float)(b)[1], fmaf((float)(a)[0], (float)(b)[0], (c)))
#endif

// k_tokens: packed-fp32 math (r15). This round: wi moved OUT of LDS to
// wave-uniform scalar loads (12KB/blk fits scalar cache; bit-identical math)
// -> LDS 40768 -> 4 blocks/CU, grid 1024 = all blocks co-resident.
// Pre-commit: revert wi to LDS if k_tokens regresses (r5 measured the LDS
// variant neutral in the OLD VALU-bound regime; now latency-bound).
// V stays fp32 (round-4). latent+dots: split-fp16 MFMA w/ pre-split B (r14-16).
// Decoder: fp16-MFMA end to end (r10-r12).
#define KSTR 36
#define VSTR 34
#define KBYTES (49 * 72)
#define WAVE_LDS (49 * 72 + 49 * 136)  // 10192
#define BLOCK_LDS (4 * WAVE_LDS)       // 40768 -> 4 blocks/CU

// ---------------------------------------------------------------------------
// Fused: patch conv (1->32, k4 s4) + 2 transformer blocks. Packed-fp32 math.
// ---------------------------------------------------------------------------
__global__ __launch_bounds__(256) void k_tokens(
    const float* __restrict__ x, const float* __restrict__ pw, const float* __restrict__ pb,
    const float* __restrict__ ln1g, const float* __restrict__ ln1b,
    const float* __restrict__ wi, const float* __restrict__ bi,
    const float* __restrict__ wo, const float* __restrict__ bo,
    const float* __restrict__ ln2g, const float* __restrict__ ln2b,
    const float* __restrict__ w1, const float* __restrict__ fb1,
    const float* __restrict__ w2t, const float* __restrict__ fb2,
    float* __restrict__ tokens)
{
    __shared__ __align__(16) unsigned char Lraw[BLOCK_LDS];
    const int tid = threadIdx.x;
    const int wv = tid >> 6, lane = tid & 63;
    const int b = blockIdx.x * 4 + wv;
    half_t* Kb = (half_t*)(Lraw + wv * WAVE_LDS);
    float*  Vb = (float*)(Lraw + wv * WAVE_LDS + KBYTES);
    float* Lf = (float*)Lraw;            // FF-weight overlay (block-wide)
    const bool is_tok = lane < 49;
    const int s = is_tok ? lane : 48;
    const int py = s / 7, px = s % 7;

    // --- patch conv: direct float4 loads; packed accumulate ---
    f2v xv2[8];
    const float* xb = x + (size_t)b * 784 + py * 112 + px * 4;
    #pragma unroll
    for (int r = 0; r < 4; ++r) {
        float4 vq = *(const float4*)(xb + r * 28);
        f2v lo; lo[0] = vq.x; lo[1] = vq.y;
        f2v hi; hi[0] = vq.z; hi[1] = vq.w;
        xv2[2 * r] = lo; xv2[2 * r + 1] = hi;
    }
    f2v t2[16];
    #pragma unroll
    for (int c = 0; c < 32; ++c) {
        const float* wr = pw + c * 16;
        f2v a2 = (f2v){0.f, 0.f};
        #pragma unroll
        for (int c2 = 0; c2 < 4; ++c2) {
            float4 wq = *(const float4*)&wr[4 * c2];
            f2v w0; w0[0] = wq.x; w0[1] = wq.y;
            f2v w1v; w1v[0] = wq.z; w1v[1] = wq.w;
            a2 += xv2[2 * c2] * w0;
            a2 += xv2[2 * c2 + 1] * w1v;
        }
        t2[c >> 1][c & 1] = pb[c] + a2[0] + a2[1];
    }

    for (int blk = 0; blk < 2; ++blk) {
        const float* bib = bi + blk * 96;
        const float* wib = wi + blk * 3072;   // wave-uniform scalar loads

        // --- LN1 ---
        f2v mu2 = (f2v){0.f, 0.f};
        #pragma unroll
        for (int i = 0; i < 16; ++i) mu2 += t2[i];
        float mu = (mu2[0] + mu2[1]) * 0.03125f;
        f2v mub; mub[0] = mu; mub[1] = mu;
        f2v var2 = (f2v){0.f, 0.f};
        #pragma unroll
        for (int i = 0; i < 16; ++i) { f2v d = t2[i] - mub; var2 += d * d; }
        float rstd = rsqrtf((var2[0] + var2[1]) * 0.03125f + 1e-5f);
        f2v rstd2; rstd2[0] = rstd; rstd2[1] = rstd;
        f2v xn2[16];
        {
            const f2v* g2 = (const f2v*)(ln1g + blk * 32);
            const f2v* bl2 = (const f2v*)(ln1b + blk * 32);
            #pragma unroll
            for (int i = 0; i < 16; ++i)
                xn2[i] = (t2[i] - mub) * rstd2 * g2[i] + bl2[i];
        }

        __syncthreads();   // (A) prior-phase FF-overlay reads done before K/V overwrite

        // --- K projection -> LDS fp16 (wave-uniform weight rows) ---
        #pragma unroll 4
        for (int d = 0; d < 32; ++d) {
            const float* wr = wib + (32 + d) * 32;
            f2v a2 = (f2v){0.f, 0.f};
            #pragma unroll
            for (int c2 = 0; c2 < 8; ++c2) {
                float4 wq = *(const float4*)&wr[4 * c2];
                f2v w0; w0[0] = wq.x; w0[1] = wq.y;
                f2v w1v; w1v[0] = wq.z; w1v[1] = wq.w;
                a2 += xn2[2 * c2] * w0;
                a2 += xn2[2 * c2 + 1] * w1v;
            }
            if (is_tok) Kb[s * KSTR + d] = (half_t)(bib[32 + d] + a2[0] + a2[1]);
        }
        // --- V projection -> LDS fp32 ---
        #pragma unroll 4
        for (int d = 0; d < 32; ++d) {
            const float* wr = wib + (64 + d) * 32;
            f2v a2 = (f2v){0.f, 0.f};
            #pragma unroll
            for (int c2 = 0; c2 < 8; ++c2) {
                float4 wq = *(const float4*)&wr[4 * c2];
                f2v w0; w0[0] = wq.x; w0[1] = wq.y;
                f2v w1v; w1v[0] = wq.z; w1v[1] = wq.w;
                a2 += xn2[2 * c2] * w0;
                a2 += xn2[2 * c2 + 1] * w1v;
            }
            if (is_tok) Vb[s * VSTR + d] = bib[64 + d] + a2[0] + a2[1];
        }
        // --- Q projection (scaled) ---
        float q0[32];
        #pragma unroll 4
        for (int d = 0; d < 32; ++d) {
            const float* wr = wib + d * 32;
            f2v a2 = (f2v){0.f, 0.f};
            #pragma unroll
            for (int c2 = 0; c2 < 8; ++c2) {
                float4 wq = *(const float4*)&wr[4 * c2];
                f2v w0; w0[0] = wq.x; w0[1] = wq.y;
                f2v w1v; w1v[0] = wq.z; w1v[1] = wq.w;
                a2 += xn2[2 * c2] * w0;
                a2 += xn2[2 * c2 + 1] * w1v;
            }
            q0[d] = (bib[d] + a2[0] + a2[1]) * 0.25f;
        }
        h2 qh[16];
        #pragma unroll
        for (int i = 0; i < 16; ++i) {
            h2 hh; hh[0] = (half_t)q0[2 * i]; hh[1] = (half_t)q0[2 * i + 1];
            qh[i] = hh;
        }

        // wave-local fence: own K/V ds_writes visible before broadcast reads
        __asm__ volatile("s_waitcnt lgkmcnt(0)" ::: "memory");

        // --- attention: 2 heads of 16 dims; packed PV ---
        f2v o2[16];
        #pragma unroll
        for (int i = 0; i < 16; ++i) o2[i] = (f2v){0.f, 0.f};
        float l0 = 0.f, l1 = 0.f;
        union H4 { double qd; h2 p[2]; };
        for (int j = 0; j < 49; ++j) {
            const double* kr = (const double*)(Kb + j * KSTR);
            const float* vr = Vb + j * VSTR;
            H4 u0, u1, u2, u3, w0, w1h, w2h, w3;
            u0.qd = kr[0]; u1.qd = kr[1]; u2.qd = kr[2]; u3.qd = kr[3];
            w0.qd = kr[4]; w1h.qd = kr[5]; w2h.qd = kr[6]; w3.qd = kr[7];
            float s0a = 0.f, s0b = 0.f, s1a = 0.f, s1b = 0.f;
            s0a = FDOT2(u0.p[0], qh[0], s0a); s0a = FDOT2(u0.p[1], qh[1], s0a);
            s0b = FDOT2(u1.p[0], qh[2], s0b); s0b = FDOT2(u1.p[1], qh[3], s0b);
            s0a = FDOT2(u2.p[0], qh[4], s0a); s0a = FDOT2(u2.p[1], qh[5], s0a);
            s0b = FDOT2(u3.p[0], qh[6], s0b); s0b = FDOT2(u3.p[1], qh[7], s0b);
            s1a = FDOT2(w0.p[0], qh[8], s1a); s1a = FDOT2(w0.p[1], qh[9], s1a);
            s1b = FDOT2(w1h.p[0], qh[10], s1b); s1b = FDOT2(w1h.p[1], qh[11], s1b);
            s1a = FDOT2(w2h.p[0], qh[12], s1a); s1a = FDOT2(w2h.p[1], qh[13], s1a);
            s1b = FDOT2(w3.p[0], qh[14], s1b); s1b = FDOT2(w3.p[1], qh[15], s1b);
            float p0 = __expf(s0a + s0b), p1 = __expf(s1a + s1b);
            l0 += p0; l1 += p1;
            f2v p02; p02[0] = p0; p02[1] = p0;
            f2v p12; p12[0] = p1; p12[1] = p1;
            #pragma unroll
            for (int i = 0; i < 8; ++i) {
                f2v va = *(const f2v*)&vr[2 * i];
                o2[i] += p02 * va;
                f2v vc = *(const f2v*)&vr[16 + 2 * i];
                o2[8 + i] += p12 * vc;
            }
        }
        {
            float il0 = 1.f / l0, il1 = 1.f / l1;
            f2v il02; il02[0] = il0; il02[1] = il0;
            f2v il12; il12[0] = il1; il12[1] = il1;
            #pragma unroll
            for (int i = 0; i < 8; ++i) { o2[i] *= il02; o2[8 + i] *= il12; }
        }

        // --- out projection + residual ---
        #pragma unroll
        for (int c = 0; c < 32; ++c) {
            const float* wr = wo + blk * 1024 + c * 32;
            f2v a2 = (f2v){0.f, 0.f};
            #pragma unroll
            for (int c2 = 0; c2 < 8; ++c2) {
                float4 wq = *(const float4*)&wr[4 * c2];
                f2v w0; w0[0] = wq.x; w0[1] = wq.y;
                f2v w1v; w1v[0] = wq.z; w1v[1] = wq.w;
                a2 += o2[2 * c2] * w0;
                a2 += o2[2 * c2 + 1] * w1v;
            }
            t2[c >> 1][c & 1] += bo[blk * 32 + c] + a2[0] + a2[1];
        }

        // --- LN2 ---
        mu2 = (f2v){0.f, 0.f};
        #pragma unroll
        for (int i = 0; i < 16; ++i) mu2 += t2[i];
        mu = (mu2[0] + mu2[1]) * 0.03125f;
        mub[0] = mu; mub[1] = mu;
        var2 = (f2v){0.f, 0.f};
        #pragma unroll
        for (int i = 0; i < 16; ++i) { f2v d = t2[i] - mub; var2 += d * d; }
        rstd = rsqrtf((var2[0] + var2[1]) * 0.03125f + 1e-5f);
        rstd2[0] = rstd; rstd2[1] = rstd;
        {
            const f2v* g2 = (const f2v*)(ln2g + blk * 32);
            const f2v* bl2 = (const f2v*)(ln2b + blk * 32);
            #pragma unroll
            for (int i = 0; i < 16; ++i)
                xn2[i] = (t2[i] - mub) * rstd2 * g2[i] + bl2[i];
        }

        __syncthreads();   // (C) all waves done reading K/V

        // --- stage FF weights (overlay over KV) ---
        {
            const float4* src1 = (const float4*)(w1 + blk * 4096);
            const float4* src2 = (const float4*)(w2t + blk * 4096);
            float4* dst = (float4*)Lraw;
            for (int e = tid; e < 1024; e += 256) dst[e] = src1[e];
            for (int e = tid; e < 1024; e += 256) dst[1024 + e] = src2[e];
        }
        __syncthreads();   // (D) FF weights visible

        // --- FF from LDS: packed dot + packed axpy ---
        const float* w2L = Lf + 4096;
        #pragma unroll 2
        for (int j = 0; j < 128; ++j) {
            const float* wr = Lf + j * 32;
            f2v h2a = (f2v){0.f, 0.f};
            #pragma unroll
            for (int c2 = 0; c2 < 8; ++c2) {
                float4 wq = *(const float4*)&wr[4 * c2];
                f2v w0; w0[0] = wq.x; w0[1] = wq.y;
                f2v w1v; w1v[0] = wq.z; w1v[1] = wq.w;
                h2a += xn2[2 * c2] * w0;
                h2a += xn2[2 * c2 + 1] * w1v;
            }
            float h = fb1[blk * 128 + j] + h2a[0] + h2a[1];
            h = 0.5f * h * (1.f + erff(h * 0.7071067811865476f));
            f2v hh; hh[0] = h; hh[1] = h;
            const float* w2r = w2L + j * 32;
            #pragma unroll
            for (int c2 = 0; c2 < 8; ++c2) {
                float4 wq = *(const float4*)&w2r[4 * c2];
                f2v w0; w0[0] = wq.x; w0[1] = wq.y;
                f2v w1v; w1v[0] = wq.z; w1v[1] = wq.w;
                t2[2 * c2]     += hh * w0;
                t2[2 * c2 + 1] += hh * w1v;
            }
        }
        {
            const f2v* fb22 = (const f2v*)(fb2 + blk * 32);
            #pragma unroll
            for (int i = 0; i < 16; ++i) t2[i] += fb22[i];
        }
    }

    if (is_tok) {
        float* op = tokens + (size_t)b * 1568 + s * 32;
        #pragma unroll
        for (int i = 0; i < 8; ++i) {
            float4 vv = make_float4(t2[2 * i][0], t2[2 * i][1],
                                    t2[2 * i + 1][0], t2[2 * i + 1][1]);
            *(float4*)&op[4 * i] = vv;
        }
    }
}

// ---------------------------------------------------------------------------
// Pre-split lat_w and memory into fp16 hi/lo pairs AND compute inv_norm
// (merged k_mnorm: block b covers exactly memory row b; identical reduction
// tree -> bit-identical inv_norm).
// ---------------------------------------------------------------------------
__global__ __launch_bounds__(256) void k_split(
    const float* __restrict__ lat_w, const float* __restrict__ memory,
    half_t* __restrict__ lwh, half_t* __restrict__ lwl,
    half_t* __restrict__ memh, half_t* __restrict__ meml,
    float* __restrict__ inv_norm)
{
    __shared__ float red[256];
    const int tid = threadIdx.x;
    size_t i = (size_t)blockIdx.x * 256 + tid;
    if (i < 401408) {   // 256*1568
        float v = lat_w[i];
        half_t h = (half_t)v;
        lwh[i] = h; lwl[i] = (half_t)((v - (float)h) * 2048.0f);
    }
    float v = 0.f;
    if (i < 1048576) {  // 4096*256  (block b == memory row b)
        v = memory[i];
        half_t h = (half_t)v;
        memh[i] = h; meml[i] = (half_t)((v - (float)h) * 2048.0f);
    }
    if (blockIdx.x < 4096) {
        red[tid] = v * v;
        __syncthreads();
        for (int s = 128; s > 0; s >>= 1) {
            if (tid < s) red[tid] += red[tid + s];
            __syncthreads();
        }
        if (tid == 0) inv_norm[blockIdx.x] = 1.f / fmaxf(sqrtf(red[0]), 1e-12f);
    }
}

// ---------------------------------------------------------------------------
// SPLIT-fp16 MFMA GEMM with PRE-SPLIT B: C = A @ B^T (+bias), fp32 out.
// ---------------------------------------------------------------------------
__global__ __launch_bounds__(256) void k_sgemm(
    const float* __restrict__ A, const half_t* __restrict__ Bhg,
    const half_t* __restrict__ Blg, const float* __restrict__ bias,
    float* __restrict__ C, int M, int N, int K)
{
    __shared__ __align__(16) half_t Ah[64 * 40];
    __shared__ __align__(16) half_t Al[64 * 40];
    __shared__ __align__(16) half_t Bh[128 * 40];
    __shared__ __align__(16) half_t Bl[128 * 40];
    const int tid = threadIdx.x;
    const int n0 = blockIdx.x * 128, m0 = blockIdx.y * 64;
    const int w = tid >> 6, lane = tid & 63;
    const int wm = (w >> 1) * 32, wn = (w & 1) * 64;
    const int lr = lane & 15, lk = lane >> 4;

    const int ar = tid >> 2, aseg = (tid & 3) * 8;
    const int br = tid >> 1, bseg = (tid & 1) * 16;

    f4v acch[2][4], accm[2][4];
    #pragma unroll
    for (int i = 0; i < 2; ++i)
        #pragma unroll
        for (int j = 0; j < 4; ++j) {
            acch[i][j] = (f4v){0.f, 0.f, 0.f, 0.f};
            accm[i][j] = (f4v){0.f, 0.f, 0.f, 0.f};
        }

    for (int k0 = 0; k0 < K; k0 += 32) {
        {
            const float* ap = A + (size_t)(m0 + ar) * K + k0 + aseg;
            float4 a0 = *(const float4*)ap;
            float4 a1 = *(const float4*)(ap + 4);
            float av[8] = {a0.x, a0.y, a0.z, a0.w, a1.x, a1.y, a1.z, a1.w};
            h8v ah, al;
            #pragma unroll
            for (int i = 0; i < 8; ++i) {
                half_t h = (half_t)av[i];
                ah[i] = h;
                al[i] = (half_t)((av[i] - (float)h) * 2048.0f);
            }
            *(h8v*)&Ah[ar * 40 + aseg] = ah;
            *(h8v*)&Al[ar * 40 + aseg] = al;

            const half_t* bph = Bhg + (size_t)(n0 + br) * K + k0 + bseg;
            const half_t* bpl = Blg + (size_t)(n0 + br) * K + k0 + bseg;
            h8v bh0 = *(const h8v*)bph;
            h8v bh1 = *(const h8v*)(bph + 8);
            h8v bl0 = *(const h8v*)bpl;
            h8v bl1 = *(const h8v*)(bpl + 8);
            *(h8v*)&Bh[br * 40 + bseg]     = bh0;
            *(h8v*)&Bh[br * 40 + bseg + 8] = bh1;
            *(h8v*)&Bl[br * 40 + bseg]     = bl0;
            *(h8v*)&Bl[br * 40 + bseg + 8] = bl1;
        }
        __syncthreads();
        h8v afh[2], afl[2], bfh[4], bfl[4];
        #pragma unroll
        for (int i = 0; i < 2; ++i) {
            afh[i] = *(const h8v*)&Ah[(wm + i * 16 + lr) * 40 + lk * 8];
            afl[i] = *(const h8v*)&Al[(wm + i * 16 + lr) * 40 + lk * 8];
        }
        #pragma unroll
        for (int j = 0; j < 4; ++j) {
            bfh[j] = *(const h8v*)&Bh[(wn + j * 16 + lr) * 40 + lk * 8];
            bfl[j] = *(const h8v*)&Bl[(wn + j * 16 + lr) * 40 + lk * 8];
        }
        #pragma unroll
        for (int i = 0; i < 2; ++i)
            #pragma unroll
            for (int j = 0; j < 4; ++j) {
                acch[i][j] = __builtin_amdgcn_mfma_f32_16x16x32_f16(afh[i], bfh[j], acch[i][j], 0, 0, 0);
                accm[i][j] = __builtin_amdgcn_mfma_f32_16x16x32_f16(afh[i], bfl[j], accm[i][j], 0, 0, 0);
                accm[i][j] = __builtin_amdgcn_mfma_f32_16x16x32_f16(afl[i], bfh[j], accm[i][j], 0, 0, 0);
            }
        __syncthreads();
    }

    #pragma unroll
    for (int j = 0; j < 4; ++j) {
        int n = n0 + wn + j * 16 + lr;
        float bv = bias ? bias[n] : 0.f;
        #pragma unroll
        for (int i = 0; i < 2; ++i) {
            #pragma unroll
            for (int r = 0; r < 4; ++r) {
                int m = m0 + wm + i * 16 + lk * 4 + r;
                C[(size_t)m * N + n] = acch[i][j][r] + accm[i][j][r] * (1.0f / 2048.0f) + bv;
            }
        }
    }
}

// ---------------------------------------------------------------------------
// MFMA decoder GEMM: d1h[M,N] = (fp16)relu(A[M,K] @ B[N,K]^T + bias).
// ---------------------------------------------------------------------------
__global__ __launch_bounds__(256) void k_dgemm(
    const float* __restrict__ A, const float* __restrict__ Bm,
    const float* __restrict__ bias, half_t* __restrict__ C,
    int M, int N, int K)
{
    __shared__ __align__(16) half_t As[64 * 40];
    __shared__ __align__(16) half_t Bs[128 * 40];
    const int tid = threadIdx.x;
    const int n0 = blockIdx.x * 128, m0 = blockIdx.y * 64;
    const int w = tid >> 6, lane = tid & 63;
    const int wm = (w >> 1) * 32, wn = (w & 1) * 64;
    const int lr = lane & 15, lk = lane >> 4;

    const int ar = tid >> 2, aseg = (tid & 3) * 8;
    const int br = tid >> 1, bseg = (tid & 1) * 16;

    f4v acc[2][4];
    #pragma unroll
    for (int i = 0; i < 2; ++i)
        #pragma unroll
        for (int j = 0; j < 4; ++j) acc[i][j] = (f4v){0.f, 0.f, 0.f, 0.f};

    for (int k0 = 0; k0 < K; k0 += 32) {
        {
            const float* ap = A + (size_t)(m0 + ar) * K + k0 + aseg;
            float4 a0 = *(const float4*)ap;
            float4 a1 = *(const float4*)(ap + 4);
            h8v ha;
            ha[0] = (half_t)a0.x; ha[1] = (half_t)a0.y;
            ha[2] = (half_t)a0.z; ha[3] = (half_t)a0.w;
            ha[4] = (half_t)a1.x; ha[5] = (half_t)a1.y;
            ha[6] = (half_t)a1.z; ha[7] = (half_t)a1.w;
            *(h8v*)&As[ar * 40 + aseg] = ha;

            const float* bp = Bm + (size_t)(n0 + br) * K + k0 + bseg;
            float4 b0 = *(const float4*)bp;
            float4 b1 = *(const float4*)(bp + 4);
            float4 b2 = *(const float4*)(bp + 8);
            float4 b3 = *(const float4*)(bp + 12);
            h8v hb0, hb1;
            hb0[0] = (half_t)b0.x; hb0[1] = (half_t)b0.y;
            hb0[2] = (half_t)b0.z; hb0[3] = (half_t)b0.w;
            hb0[4] = (half_t)b1.x; hb0[5] = (half_t)b1.y;
            hb0[6] = (half_t)b1.z; hb0[7] = (half_t)b1.w;
            hb1[0] = (half_t)b2.x; hb1[1] = (half_t)b2.y;
            hb1[2] = (half_t)b2.z; hb1[3] = (half_t)b2.w;
            hb1[4] = (half_t)b3.x; hb1[5] = (half_t)b3.y;
            hb1[6] = (half_t)b3.z; hb1[7] = (half_t)b3.w;
            *(h8v*)&Bs[br * 40 + bseg] = hb0;
            *(h8v*)&Bs[br * 40 + bseg + 8] = hb1;
        }
        __syncthreads();
        h8v af[2], bfr[4];
        #pragma unroll
        for (int i = 0; i < 2; ++i)
            af[i] = *(const h8v*)&As[(wm + i * 16 + lr) * 40 + lk * 8];
        #pragma unroll
        for (int j = 0; j < 4; ++j)
            bfr[j] = *(const h8v*)&Bs[(wn + j * 16 + lr) * 40 + lk * 8];
        #pragma unroll
        for (int i = 0; i < 2; ++i)
            #pragma unroll
            for (int j = 0; j < 4; ++j)
                acc[i][j] = __builtin_amdgcn_mfma_f32_16x16x32_f16(af[i], bfr[j], acc[i][j], 0, 0, 0);
        __syncthreads();
    }

    #pragma unroll
    for (int j = 0; j < 4; ++j) {
        int n = n0 + wn + j * 16 + lr;
        float bv = bias[n];
        #pragma unroll
        for (int i = 0; i < 2; ++i) {
            #pragma unroll
            for (int r = 0; r < 4; ++r) {
                int m = m0 + wm + i * 16 + lk * 4 + r;
                C[(size_t)m * N + n] = (half_t)fmaxf(acc[i][j][r] + bv, 0.f);
            }
        }
    }
}

// ---------------------------------------------------------------------------
// Fuse dec (linear 256->3136) with convt1. Packed f2v accumulators.
// ---------------------------------------------------------------------------
__global__ __launch_bounds__(256) void k_fuse(
    const float* __restrict__ wt1, const float* __restrict__ upt1_b,
    const float* __restrict__ dec_w, const float* __restrict__ dec_b,
    float* __restrict__ Wf, float* __restrict__ bf)
{
    __shared__ float WL[4][64][32];
    const int p = blockIdx.x;
    const int k = threadIdx.x;
    const int y = p / 14, x = p % 14;

    int ky0 = 0, iy0 = 0, ky1 = 0, iy1 = 0, nky = 0;
    for (int ky = 0; ky < 4; ++ky) {
        int iyn = y + 1 - ky;
        if (iyn < 0 || (iyn & 1)) continue;
        int iy = iyn >> 1;
        if (iy > 6) continue;
        if (nky == 0) { ky0 = ky; iy0 = iy; } else { ky1 = ky; iy1 = iy; }
        ++nky;
    }
    int kx0 = 0, ix0 = 0, kx1 = 0, ix1 = 0, nkx = 0;
    for (int kx = 0; kx < 4; ++kx) {
        int ixn = x + 1 - kx;
        if (ixn < 0 || (ixn & 1)) continue;
        int ix = ixn >> 1;
        if (ix > 6) continue;
        if (nkx == 0) { kx0 = kx; ix0 = ix; } else { kx1 = kx; ix1 = ix; }
        ++nkx;
    }
    const int ntap = nky * nkx;

    for (int e = k; e < ntap * 2048; e += 256) {
        int t = e >> 11, c = (e >> 5) & 63, o = e & 31;
        int ti = (nkx == 2) ? (t >> 1) : t;
        int tj = (nkx == 2) ? (t & 1) : 0;
        int ky = ti ? ky1 : ky0;
        int kx = tj ? kx1 : kx0;
        WL[t][c][o] = wt1[((c * 32 + o) * 4 + ky) * 4 + kx];
    }
    __syncthreads();

    f2v acc2[16];
    #pragma unroll
    for (int o = 0; o < 16; ++o) acc2[o] = (f2v){0.f, 0.f};
    float bacc = 0.f;

    for (int t = 0; t < ntap; ++t) {
        int ti = (nkx == 2) ? (t >> 1) : t;
        int tj = (nkx == 2) ? (t & 1) : 0;
        int iy = ti ? iy1 : iy0;
        int ix = tj ? ix1 : ix0;
        int rbase = iy * 7 + ix;
        for (int c = 0; c < 64; ++c) {
            int row = c * 49 + rbase;
            float v = dec_w[(size_t)row * 256 + k];
            f2v vv; vv[0] = v; vv[1] = v;
            const f2v* w2p = (const f2v*)&WL[t][c][0];
            #pragma unroll
            for (int o2 = 0; o2 < 16; ++o2) acc2[o2] += vv * w2p[o2];
            if (k < 32) bacc = fmaf(WL[t][c][k], dec_b[row], bacc);
        }
    }

    #pragma unroll 4
    for (int o = 0; o < 32; ++o)
        Wf[((size_t)(p * 32 + o)) * 256 + k] = acc2[o >> 1][o & 1];
    if (k < 32) bf[p * 32 + k] = bacc + upt1_b[k];
}

// ---------------------------------------------------------------------------
// Top-k via wave __shfl_xor lexicographic (v,idx) reduce (exactly associative).
// ---------------------------------------------------------------------------
__global__ __launch_bounds__(256) void k_memread(
    const float* __restrict__ latent, const float* __restrict__ dots,
    const float* __restrict__ inv_mn, const float* __restrict__ mem,
    float* __restrict__ out)
{
    __shared__ float red[256];
    __shared__ int   redi[4];
    __shared__ float inv_x_s;
    const int b = blockIdx.x, tid = threadIdx.x;
    const int w = tid >> 6, lane = tid & 63;
    float lx = latent[(size_t)b * 256 + tid];
    red[tid] = lx * lx;
    __syncthreads();
    for (int s = 128; s > 0; s >>= 1) {
        if (tid < s) red[tid] += red[tid + s];
        __syncthreads();
    }
    if (tid == 0) inv_x_s = 1.f / fmaxf(sqrtf(red[0]), 1e-12f);
    __syncthreads();
    const float inv_x = inv_x_s;

    float vals[16];
    for (int j = 0; j < 16; ++j) {
        int m = tid + j * 256;
        vals[j] = dots[(size_t)b * 4096 + m] * inv_mn[m] * inv_x;
    }
    float tv[10]; int ti[10];
    for (int t = 0; t < 10; ++t) {
        float bv = -1e30f; int bidx = 0x7fffffff;
        #pragma unroll
        for (int j = 0; j < 16; ++j) {
            int m = tid + j * 256;
            float v = vals[j];
            if (v > bv || (v == bv && m < bidx)) { bv = v; bidx = m; }
        }
        #pragma unroll
        for (int off = 32; off > 0; off >>= 1) {
            float ov = __shfl_xor(bv, off);
            int   oi = __shfl_xor(bidx, off);
            if (ov > bv || (ov == bv && oi < bidx)) { bv = ov; bidx = oi; }
        }
        if (lane == 0) { red[w] = bv; redi[w] = bidx; }
        __syncthreads();
        float fv = red[0]; int fi = redi[0];
        #pragma unroll
        for (int q = 1; q < 4; ++q) {
            float v2 = red[q]; int i2 = redi[q];
            if (v2 > fv || (v2 == fv && i2 < fi)) { fv = v2; fi = i2; }
        }
        tv[t] = fv; ti[t] = fi;
        if ((fi & 255) == tid) vals[fi >> 8] = -1e30f;
        __syncthreads();
    }
    float wgt[10], wsum = 0.f;
    for (int t = 0; t < 10; ++t) { wgt[t] = expf(tv[t] - tv[0]); wsum += wgt[t]; }
    float inv_ws = 1.f / wsum;
    float acc = 0.f;
    for (int t = 0; t < 10; ++t) acc += (wgt[t] * inv_ws) * mem[(size_t)ti[t] * 256 + tid];
    out[(size_t)b * 256 + tid] = acc;
}

// ---------------------------------------------------------------------------
// Weight repack.
// ---------------------------------------------------------------------------
__global__ __launch_bounds__(256) void k_pack(
    const float* __restrict__ wc1, const float* __restrict__ wt2,
    const float* __restrict__ wc2, const float* __restrict__ w2src,
    half_t* __restrict__ pk2h, half_t* __restrict__ pk3h,
    float* __restrict__ pk4, float* __restrict__ pk5)
{
    int i = blockIdx.x * 256 + threadIdx.x;
    if (i < 9216) {
        int ic = i & 31, oc = (i >> 5) & 15, nt = (i >> 9) & 1, t = i >> 10;
        pk2h[i] = (half_t)wc1[((nt * 16 + oc) * 32 + ic) * 9 + t];
    }
    if (i < 8192) {
        int ic = i & 31, oc = (i >> 5) & 15, t = (i >> 9) & 3, q = i >> 11;
        int wy = t >> 1, wx = t & 1, py = q >> 1, px = q & 1;
        int ky = 3 - py - 2 * wy, kx = 3 - px - 2 * wx;
        pk3h[i] = (half_t)wt2[((ic * 16 + oc) * 4 + ky) * 4 + kx];
    }
    if (i < 1152) {
        int o = i & 7, tap = (i >> 3) % 9, c = i / 72;
        pk4[i] = wc2[(o * 16 + c) * 9 + tap];
    }
    if (i < 8192) {
        int c = i & 31, j = (i >> 5) & 127, bq = i >> 12;
        pk5[i] = w2src[bq * 4096 + c * 128 + j];
    }
}

// ---------------------------------------------------------------------------
// Conv2d 32->32 k3 p1, 14x14, ReLU — MFMA. 2 samples/block.
// ---------------------------------------------------------------------------
__global__ __launch_bounds__(256) void k_conv1(
    const half_t* __restrict__ in, const half_t* __restrict__ wh,
    const float* __restrict__ bias, half_t* __restrict__ out)
{
    __shared__ __align__(16) half_t P[2 * 16 * 16 * 40];
    const int tid = threadIdx.x;
    const int w = tid >> 6, lane = tid & 63;
    const size_t b0 = (size_t)blockIdx.x * 2;

    for (int e = tid; e < 10240; e += 256) ((unsigned int*)P)[e] = 0u;
    __syncthreads();
    {
        const unsigned int* src = (const unsigned int*)in;
        for (int e = tid; e < 6272; e += 256) {
            int si = e / 3136;
            int rem = e - si * 3136;
            int p = rem >> 4, c2 = rem & 15;
            int y = p / 14, x = p % 14;
            ((unsigned int*)P)[si * 5120 + ((y + 1) * 16 + (x + 1)) * 20 + c2] =
                src[(b0 + si) * 3136 + rem];
        }
    }

    h8v bfr[9][2];
    #pragma unroll
    for (int t = 0; t < 9; ++t)
        #pragma unroll
        for (int nt = 0; nt < 2; ++nt)
            bfr[t][nt] = *(const h8v*)&wh[((size_t)((t * 2 + nt) * 16 + (lane & 15))) * 32 + (lane >> 4) * 8];

    __syncthreads();

    const int kseg = (lane >> 4) * 8;
    const int oc = lane & 15;
    const float bv0 = bias[oc], bv1 = bias[16 + oc];

    for (int job = w; job < 26; job += 4) {
        const int si = job >= 13 ? 1 : 0;
        const int tile = job - si * 13;
        int p = tile * 16 + (lane & 15);
        if (p > 195) p = 195;
        const int y = p / 14, x = p % 14;
        const half_t* Pb = P + si * 10240;

        f4v acc0 = (f4v){0.f, 0.f, 0.f, 0.f};
        f4v acc1 = (f4v){0.f, 0.f, 0.f, 0.f};
        #pragma unroll
        for (int ky = 0; ky < 3; ++ky) {
            #pragma unroll
            for (int kx = 0; kx < 3; ++kx) {
                h8v af = *(const h8v*)&Pb[((y + ky) * 16 + (x + kx)) * 40 + kseg];
                acc0 = __builtin_amdgcn_mfma_f32_16x16x32_f16(af, bfr[ky * 3 + kx][0], acc0, 0, 0, 0);
                acc1 = __builtin_amdgcn_mfma_f32_16x16x32_f16(af, bfr[ky * 3 + kx][1], acc1, 0, 0, 0);
            }
        }

        const int pr0 = tile * 16 + (lane >> 4) * 4;
        half_t* ob = out + (b0 + si) * 6272;
        #pragma unroll
        for (int r = 0; r < 4; ++r) {
            int pp = pr0 + r;
            if (pp < 196) {
                ob[(size_t)pp * 32 + oc]      = (half_t)fmaxf(acc0[r] + bv0, 0.f);
                ob[(size_t)pp * 32 + 16 + oc] = (half_t)fmaxf(acc1[r] + bv1, 0.f);
            }
        }
    }
}

// ---------------------------------------------------------------------------
// FUSED: ConvTranspose2d 32->16 k4 s2 p1 (MFMA) + Conv2d 16->8 k3 p1 (ReLU,
// packed f2v) + Conv2d 8->1 k1. One sample/block.
// ---------------------------------------------------------------------------
__global__ __launch_bounds__(256) void k_convt23(
    const half_t* __restrict__ in, const half_t* __restrict__ pk3h,
    const float* __restrict__ bt2, const float* __restrict__ pk4,
    const float* __restrict__ b2, const float* __restrict__ w3,
    const float* __restrict__ b3, float* __restrict__ out)
{
    __shared__ __align__(16) unsigned char Lraw[30720];
    half_t* Pin = (half_t*)Lraw;
    float*  P2  = (float*)Lraw;
    const int tid = threadIdx.x;
    const int w = tid >> 6, lane = tid & 63;
    const int b = blockIdx.x;

    for (int e = tid; e < 5120; e += 256) ((unsigned int*)Pin)[e] = 0u;
    __syncthreads();
    {
        const unsigned int* src = (const unsigned int*)in;
        for (int e = tid; e < 3136; e += 256) {
            int p = e >> 4, c2 = e & 15;
            int y = p / 14, x = p % 14;
            ((unsigned int*)Pin)[((y + 1) * 16 + (x + 1)) * 20 + c2] =
                src[(size_t)b * 3136 + e];
        }
    }
    __syncthreads();

    const int oc = lane & 15;
    const int kseg = (lane >> 4) * 8;

    f4v res[13];
    #pragma unroll
    for (int j = 0; j < 13; ++j) {
        const int job = w + 4 * j;
        const int q = job / 13, tile = job - q * 13;
        const int py = q >> 1, px = q & 1;
        int p = tile * 16 + (lane & 15);
        if (p > 195) p = 195;
        const int ty = p / 14, tx = p % 14;
        f4v a = (f4v){0.f, 0.f, 0.f, 0.f};
        #pragma unroll
        for (int t = 0; t < 4; ++t) {
            const int wy = t >> 1, wx = t & 1;
            h8v bf = *(const h8v*)&pk3h[((size_t)((q * 4 + t) * 16 + oc)) * 32 + kseg];
            h8v af = *(const h8v*)&Pin[((ty + py + wy) * 16 + (tx + px + wx)) * 40 + kseg];
            a = __builtin_amdgcn_mfma_f32_16x16x32_f16(af, bf, a, 0, 0, 0);
        }
        res[j] = a;
    }
    __syncthreads();

    const bool active2 = tid < 196;
    int row = active2 ? tid / 7 : 0;
    int tx0b = active2 ? (tid % 7) * 4 : 0;
    const float bco = bt2[oc];

    f2v acc2[4][4];
    #pragma unroll
    for (int i = 0; i < 4; ++i)
        #pragma unroll
        for (int o2 = 0; o2 < 4; ++o2) acc2[i][o2] = (f2v){0.f, 0.f};

    #pragma unroll
    for (int g = 0; g < 2; ++g) {
        for (int e = tid; e < 7680; e += 256) P2[e] = 0.f;
        __syncthreads();
        if ((oc >> 3) == g) {
            #pragma unroll
            for (int j = 0; j < 13; ++j) {
                const int job = w + 4 * j;
                const int q = job / 13, tile = job - q * 13;
                const int py = q >> 1, px = q & 1;
                const int pr0 = tile * 16 + (lane >> 4) * 4;
                #pragma unroll
                for (int r = 0; r < 4; ++r) {
                    int p = pr0 + r;
                    if (p < 196) {
                        int Y = 2 * (p / 14) + py, X = 2 * (p % 14) + px;
                        P2[((oc & 7) * 30 + Y + 1) * 32 + (X + 1)] = fmaxf(res[j][r] + bco, 0.f);
                    }
                }
            }
        }
        __syncthreads();
        for (int cl = 0; cl < 8; ++cl) {
            const float* Pb = &P2[(cl * 30 + row) * 32 + tx0b];
            const float* wb = pk4 + (size_t)(g * 8 + cl) * 72;
            #pragma unroll
            for (int ky = 0; ky < 3; ++ky) {
                float4 a = *(const float4*)&Pb[ky * 32];
                float4 bq = *(const float4*)&Pb[ky * 32 + 4];
                float rowb[8] = {a.x, a.y, a.z, a.w, bq.x, bq.y, bq.z, bq.w};
                #pragma unroll
                for (int kx = 0; kx < 3; ++kx) {
                    const f2v* wt2p = (const f2v*)(wb + (ky * 3 + kx) * 8);
                    #pragma unroll
                    for (int i = 0; i < 4; ++i) {
                        f2v rb; rb[0] = rowb[i + kx]; rb[1] = rowb[i + kx];
                        acc2[i][0] += rb * wt2p[0];
                        acc2[i][1] += rb * wt2p[1];
                        acc2[i][2] += rb * wt2p[2];
                        acc2[i][3] += rb * wt2p[3];
                    }
                }
            }
        }
        __syncthreads();
    }

    if (active2) {
        const float bias3 = b3[0];
        #pragma unroll
        for (int i = 0; i < 4; ++i) {
            float r = bias3;
            #pragma unroll
            for (int o = 0; o < 8; ++o)
                r += fmaxf(acc2[i][o >> 1][o & 1] + b2[o], 0.f) * w3[o];
            out[(size_t)b * 784 + row * 28 + tx0b + i] = r;
        }
    }
}

// ---------------------------------------------------------------------------
extern "C" void kernel_launch(void* const* d_in, const int* in_sizes, int n_in,
                              void* d_out, int out_size, void* d_ws, size_t ws_size,
                              hipStream_t stream)
{
    const float* x       = (const float*)d_in[0];
    const float* patch_w = (const float*)d_in[1];
    const float* patch_b = (const float*)d_in[2];
    const float* ln1g    = (const float*)d_in[3];
    const float* ln1b    = (const float*)d_in[4];
    const float* wi      = (const float*)d_in[5];
    const float* bi      = (const float*)d_in[6];
    const float* wo      = (const float*)d_in[7];
    const float* bo      = (const float*)d_in[8];
    const float* ln2g    = (const float*)d_in[9];
    const float* ln2b    = (const float*)d_in[10];
    const float* w1      = (const float*)d_in[11];
    const float* b1      = (const float*)d_in[12];
    const float* w2      = (const float*)d_in[13];
    const float* b2      = (const float*)d_in[14];
    const float* lat_w   = (const float*)d_in[15];
    const float* lat_b   = (const float*)d_in[16];
    const float* memory  = (const float*)d_in[17];
    const float* dec_w   = (const float*)d_in[18];
    const float* dec_b   = (const float*)d_in[19];
    const float* upt1_w  = (const float*)d_in[20];
    const float* upt1_b  = (const float*)d_in[21];
    const float* c1_w    = (const float*)d_in[22];
    const float* c1_b    = (const float*)d_in[23];
    const float* upt2_w  = (const float*)d_in[24];
    const float* upt2_b  = (const float*)d_in[25];
    const float* c2_w    = (const float*)d_in[26];
    const float* c2_b    = (const float*)d_in[27];
    const float* c3_w    = (const float*)d_in[28];
    const float* c3_b    = (const float*)d_in[29];
    float* outp = (float*)d_out;

    float* ws = (float*)d_ws;
    size_t off = 0;
    auto alloc = [&](size_t n) { float* p = ws + off; off += (n + 63) & ~(size_t)63; return p; };
    float* tokens     = alloc((size_t)B_TOT * 1568);
    float* latent     = alloc((size_t)B_TOT * 256);
    float* dots       = alloc((size_t)B_TOT * 4096);
    float* mem_latent = alloc((size_t)B_TOT * 256);
    float* inv_mn     = alloc(4096);
    half_t* pk2h      = (half_t*)alloc(4608);
    half_t* pk3h      = (half_t*)alloc(4096);
    float* pk4        = alloc(1152);
    float* pk5        = alloc(8192);
    float* Wf         = alloc((size_t)6272 * 256);
    float* bf         = alloc(6272);
    half_t* d1h       = (half_t*)alloc((size_t)CHUNK * 6272 / 2);
    half_t* d2h       = (half_t*)alloc((size_t)CHUNK * 6272 / 2);
    half_t* lwh       = (half_t*)alloc(200704);   // 256*1568 halves
    half_t* lwl       = (half_t*)alloc(200704);
    half_t* memh      = (half_t*)alloc(524288);   // 4096*256 halves
    half_t* meml      = (half_t*)alloc(524288);
    (void)in_sizes; (void)n_in; (void)out_size; (void)ws_size;

    // Prep: repack, pre-split GEMM B operands (+inv_norm), dec/convt1 fusion
    k_pack<<<36, 256, 0, stream>>>(c1_w, upt2_w, c2_w, w2, pk2h, pk3h, pk4, pk5);
    k_split<<<4096, 256, 0, stream>>>(lat_w, memory, lwh, lwl, memh, meml, inv_mn);
    k_fuse<<<196, 256, 0, stream>>>(upt1_w, upt1_b, dec_w, dec_b, Wf, bf);

    // Encoder (wave-per-sample, packed fp32 math, 4 blocks/CU)
    k_tokens<<<B_TOT / 4, 256, 0, stream>>>(x, patch_w, patch_b, ln1g, ln1b, wi, bi,
                                            wo, bo, ln2g, ln2b, w1, b1, pk5, b2, tokens);
    // latent + dots via split-fp16 MFMA with pre-split B
    k_sgemm<<<dim3(256 / 128, B_TOT / 64), 256, 0, stream>>>(tokens, lwh, lwl, lat_b,
                                                             latent, B_TOT, 256, 1568);
    k_sgemm<<<dim3(4096 / 128, B_TOT / 64), 256, 0, stream>>>(latent, memh, meml, nullptr,
                                                              dots, B_TOT, 4096, 256);
    k_memread<<<B_TOT, 256, 0, stream>>>(latent, dots, inv_mn, memory, mem_latent);

    // Decoder, full batch in one pass.
    for (int c = 0; c < B_TOT / CHUNK; ++c) {
        const float* ml = mem_latent + (size_t)c * CHUNK * 256;
        k_dgemm<<<dim3(6272 / 128, CHUNK / 64), 256, 0, stream>>>(ml, Wf, bf, d1h,
                                                                  CHUNK, 6272, 256);
        k_conv1  <<<CHUNK / 2, 256, 0, stream>>>(d1h, pk2h, c1_b, d2h);
        k_convt23<<<CHUNK, 256, 0, stream>>>(d2h, pk3h, upt2_b, pk4, c2_b, c3_w, c3_b,
                                             outp + (size_t)c * CHUNK * 784);
    }
}

// Round 18
// 1041.560 us; speedup vs baseline: 1.0705x; 1.0705x over previous
//
#include <hip/hip_runtime.h>
#include <math.h>

#define B_TOT 4096
#define CHUNK 4096

typedef _Float16 half_t;
typedef _Float16 h2 __attribute__((ext_vector_type(2)));
typedef _Float16 h8v __attribute__((ext_vector_type(8)));
typedef float f4v __attribute__((ext_vector_type(4)));
typedef float f2v __attribute__((ext_vector_type(2)));

#if __has_builtin(__builtin_amdgcn_fdot2)
#define FDOT2(a, b, c) __builtin_amdgcn_fdot2((a), (b), (c), false)
#else
#define FDOT2(a, b, c) fmaf((float)(a)[1], (float)(b)[1], fmaf((float)(a)[0], (float)(b)[0], (c)))
#endif

// REVERT to round-16 config (best measured: 1049.6us). Round-17's wi-via-
// scalar-loads regressed k_tokens 400->454 (s_load drains + scalar-cache
// thrash at 4 blocks/CU) — wi belongs in LDS; 3 blocks/CU is k_tokens'
// settled optimum across three structural variants.
// V stays fp32 (round-4). latent+dots: split-fp16 MFMA w/ pre-split B (r14-16).
// Decoder: fp16-MFMA end to end (r10-r12).
#define KSTR 36
#define VSTR 34
#define KBYTES (49 * 72)
#define WAVE_LDS (49 * 72 + 49 * 136)  // 10192
#define WI_OFF  (4 * WAVE_LDS)         // 40768
#define BLOCK_LDS (WI_OFF + 12288)     // 53056

// ---------------------------------------------------------------------------
// Fused: patch conv (1->32, k4 s4) + 2 transformer blocks. Packed-fp32 math.
// ---------------------------------------------------------------------------
__global__ __launch_bounds__(256) void k_tokens(
    const float* __restrict__ x, const float* __restrict__ pw, const float* __restrict__ pb,
    const float* __restrict__ ln1g, const float* __restrict__ ln1b,
    const float* __restrict__ wi, const float* __restrict__ bi,
    const float* __restrict__ wo, const float* __restrict__ bo,
    const float* __restrict__ ln2g, const float* __restrict__ ln2b,
    const float* __restrict__ w1, const float* __restrict__ fb1,
    const float* __restrict__ w2t, const float* __restrict__ fb2,
    float* __restrict__ tokens)
{
    __shared__ __align__(16) unsigned char Lraw[BLOCK_LDS];
    const int tid = threadIdx.x;
    const int wv = tid >> 6, lane = tid & 63;
    const int b = blockIdx.x * 4 + wv;
    half_t* Kb = (half_t*)(Lraw + wv * WAVE_LDS);
    float*  Vb = (float*)(Lraw + wv * WAVE_LDS + KBYTES);
    const float* wiL = (const float*)(Lraw + WI_OFF);
    float* Lf = (float*)Lraw;            // FF-weight overlay (block-wide)
    const bool is_tok = lane < 49;
    const int s = is_tok ? lane : 48;
    const int py = s / 7, px = s % 7;

    // --- prologue: stage blk-0 qkv weights (visible after barrier (A)) ---
    {
        const float4* srcw = (const float4*)(wi);
        float4* dstw = (float4*)(Lraw + WI_OFF);
        for (int e = tid; e < 768; e += 256) dstw[e] = srcw[e];
    }

    // --- patch conv: direct float4 loads; packed accumulate ---
    f2v xv2[8];
    const float* xb = x + (size_t)b * 784 + py * 112 + px * 4;
    #pragma unroll
    for (int r = 0; r < 4; ++r) {
        float4 vq = *(const float4*)(xb + r * 28);
        f2v lo; lo[0] = vq.x; lo[1] = vq.y;
        f2v hi; hi[0] = vq.z; hi[1] = vq.w;
        xv2[2 * r] = lo; xv2[2 * r + 1] = hi;
    }
    f2v t2[16];
    #pragma unroll
    for (int c = 0; c < 32; ++c) {
        const float* wr = pw + c * 16;
        f2v a2 = (f2v){0.f, 0.f};
        #pragma unroll
        for (int c2 = 0; c2 < 4; ++c2) {
            float4 wq = *(const float4*)&wr[4 * c2];
            f2v w0; w0[0] = wq.x; w0[1] = wq.y;
            f2v w1v; w1v[0] = wq.z; w1v[1] = wq.w;
            a2 += xv2[2 * c2] * w0;
            a2 += xv2[2 * c2 + 1] * w1v;
        }
        t2[c >> 1][c & 1] = pb[c] + a2[0] + a2[1];
    }

    for (int blk = 0; blk < 2; ++blk) {
        const float* bib = bi + blk * 96;

        // --- LN1 ---
        f2v mu2 = (f2v){0.f, 0.f};
        #pragma unroll
        for (int i = 0; i < 16; ++i) mu2 += t2[i];
        float mu = (mu2[0] + mu2[1]) * 0.03125f;
        f2v mub; mub[0] = mu; mub[1] = mu;
        f2v var2 = (f2v){0.f, 0.f};
        #pragma unroll
        for (int i = 0; i < 16; ++i) { f2v d = t2[i] - mub; var2 += d * d; }
        float rstd = rsqrtf((var2[0] + var2[1]) * 0.03125f + 1e-5f);
        f2v rstd2; rstd2[0] = rstd; rstd2[1] = rstd;
        f2v xn2[16];
        {
            const f2v* g2 = (const f2v*)(ln1g + blk * 32);
            const f2v* bl2 = (const f2v*)(ln1b + blk * 32);
            #pragma unroll
            for (int i = 0; i < 16; ++i)
                xn2[i] = (t2[i] - mub) * rstd2 * g2[i] + bl2[i];
        }

        __syncthreads();   // (A) prior-phase LDS reads done; wi stage visible

        // --- K projection -> LDS fp16 ---
        #pragma unroll 4
        for (int d = 0; d < 32; ++d) {
            const float* wr = wiL + (32 + d) * 32;
            f2v a2 = (f2v){0.f, 0.f};
            #pragma unroll
            for (int c2 = 0; c2 < 8; ++c2) {
                float4 wq = *(const float4*)&wr[4 * c2];
                f2v w0; w0[0] = wq.x; w0[1] = wq.y;
                f2v w1v; w1v[0] = wq.z; w1v[1] = wq.w;
                a2 += xn2[2 * c2] * w0;
                a2 += xn2[2 * c2 + 1] * w1v;
            }
            if (is_tok) Kb[s * KSTR + d] = (half_t)(bib[32 + d] + a2[0] + a2[1]);
        }
        // --- V projection -> LDS fp32 ---
        #pragma unroll 4
        for (int d = 0; d < 32; ++d) {
            const float* wr = wiL + (64 + d) * 32;
            f2v a2 = (f2v){0.f, 0.f};
            #pragma unroll
            for (int c2 = 0; c2 < 8; ++c2) {
                float4 wq = *(const float4*)&wr[4 * c2];
                f2v w0; w0[0] = wq.x; w0[1] = wq.y;
                f2v w1v; w1v[0] = wq.z; w1v[1] = wq.w;
                a2 += xn2[2 * c2] * w0;
                a2 += xn2[2 * c2 + 1] * w1v;
            }
            if (is_tok) Vb[s * VSTR + d] = bib[64 + d] + a2[0] + a2[1];
        }
        // --- Q projection (scaled) ---
        float q0[32];
        #pragma unroll 4
        for (int d = 0; d < 32; ++d) {
            const float* wr = wiL + d * 32;
            f2v a2 = (f2v){0.f, 0.f};
            #pragma unroll
            for (int c2 = 0; c2 < 8; ++c2) {
                float4 wq = *(const float4*)&wr[4 * c2];
                f2v w0; w0[0] = wq.x; w0[1] = wq.y;
                f2v w1v; w1v[0] = wq.z; w1v[1] = wq.w;
                a2 += xn2[2 * c2] * w0;
                a2 += xn2[2 * c2 + 1] * w1v;
            }
            q0[d] = (bib[d] + a2[0] + a2[1]) * 0.25f;
        }
        h2 qh[16];
        #pragma unroll
        for (int i = 0; i < 16; ++i) {
            h2 hh; hh[0] = (half_t)q0[2 * i]; hh[1] = (half_t)q0[2 * i + 1];
            qh[i] = hh;
        }

        // wave-local fence: own K/V ds_writes visible before broadcast reads
        __asm__ volatile("s_waitcnt lgkmcnt(0)" ::: "memory");

        // --- attention: 2 heads of 16 dims; packed PV ---
        f2v o2[16];
        #pragma unroll
        for (int i = 0; i < 16; ++i) o2[i] = (f2v){0.f, 0.f};
        float l0 = 0.f, l1 = 0.f;
        union H4 { double qd; h2 p[2]; };
        for (int j = 0; j < 49; ++j) {
            const double* kr = (const double*)(Kb + j * KSTR);
            const float* vr = Vb + j * VSTR;
            H4 u0, u1, u2, u3, w0, w1h, w2h, w3;
            u0.qd = kr[0]; u1.qd = kr[1]; u2.qd = kr[2]; u3.qd = kr[3];
            w0.qd = kr[4]; w1h.qd = kr[5]; w2h.qd = kr[6]; w3.qd = kr[7];
            float s0a = 0.f, s0b = 0.f, s1a = 0.f, s1b = 0.f;
            s0a = FDOT2(u0.p[0], qh[0], s0a); s0a = FDOT2(u0.p[1], qh[1], s0a);
            s0b = FDOT2(u1.p[0], qh[2], s0b); s0b = FDOT2(u1.p[1], qh[3], s0b);
            s0a = FDOT2(u2.p[0], qh[4], s0a); s0a = FDOT2(u2.p[1], qh[5], s0a);
            s0b = FDOT2(u3.p[0], qh[6], s0b); s0b = FDOT2(u3.p[1], qh[7], s0b);
            s1a = FDOT2(w0.p[0], qh[8], s1a); s1a = FDOT2(w0.p[1], qh[9], s1a);
            s1b = FDOT2(w1h.p[0], qh[10], s1b); s1b = FDOT2(w1h.p[1], qh[11], s1b);
            s1a = FDOT2(w2h.p[0], qh[12], s1a); s1a = FDOT2(w2h.p[1], qh[13], s1a);
            s1b = FDOT2(w3.p[0], qh[14], s1b); s1b = FDOT2(w3.p[1], qh[15], s1b);
            float p0 = __expf(s0a + s0b), p1 = __expf(s1a + s1b);
            l0 += p0; l1 += p1;
            f2v p02; p02[0] = p0; p02[1] = p0;
            f2v p12; p12[0] = p1; p12[1] = p1;
            #pragma unroll
            for (int i = 0; i < 8; ++i) {
                f2v va = *(const f2v*)&vr[2 * i];
                o2[i] += p02 * va;
                f2v vc = *(const f2v*)&vr[16 + 2 * i];
                o2[8 + i] += p12 * vc;
            }
        }
        {
            float il0 = 1.f / l0, il1 = 1.f / l1;
            f2v il02; il02[0] = il0; il02[1] = il0;
            f2v il12; il12[0] = il1; il12[1] = il1;
            #pragma unroll
            for (int i = 0; i < 8; ++i) { o2[i] *= il02; o2[8 + i] *= il12; }
        }

        // --- out projection + residual ---
        #pragma unroll
        for (int c = 0; c < 32; ++c) {
            const float* wr = wo + blk * 1024 + c * 32;
            f2v a2 = (f2v){0.f, 0.f};
            #pragma unroll
            for (int c2 = 0; c2 < 8; ++c2) {
                float4 wq = *(const float4*)&wr[4 * c2];
                f2v w0; w0[0] = wq.x; w0[1] = wq.y;
                f2v w1v; w1v[0] = wq.z; w1v[1] = wq.w;
                a2 += o2[2 * c2] * w0;
                a2 += o2[2 * c2 + 1] * w1v;
            }
            t2[c >> 1][c & 1] += bo[blk * 32 + c] + a2[0] + a2[1];
        }

        // --- LN2 ---
        mu2 = (f2v){0.f, 0.f};
        #pragma unroll
        for (int i = 0; i < 16; ++i) mu2 += t2[i];
        mu = (mu2[0] + mu2[1]) * 0.03125f;
        mub[0] = mu; mub[1] = mu;
        var2 = (f2v){0.f, 0.f};
        #pragma unroll
        for (int i = 0; i < 16; ++i) { f2v d = t2[i] - mub; var2 += d * d; }
        rstd = rsqrtf((var2[0] + var2[1]) * 0.03125f + 1e-5f);
        rstd2[0] = rstd; rstd2[1] = rstd;
        {
            const f2v* g2 = (const f2v*)(ln2g + blk * 32);
            const f2v* bl2 = (const f2v*)(ln2b + blk * 32);
            #pragma unroll
            for (int i = 0; i < 16; ++i)
                xn2[i] = (t2[i] - mub) * rstd2 * g2[i] + bl2[i];
        }

        __syncthreads();   // (C) all waves done reading K/V + wi

        // --- stage FF weights (overlay over KV) + next blk's wi ---
        {
            const float4* src1 = (const float4*)(w1 + blk * 4096);
            const float4* src2 = (const float4*)(w2t + blk * 4096);
            float4* dst = (float4*)Lraw;
            for (int e = tid; e < 1024; e += 256) dst[e] = src1[e];
            for (int e = tid; e < 1024; e += 256) dst[1024 + e] = src2[e];
            if (blk == 0) {
                const float4* srcw = (const float4*)(wi + 3072);
                float4* dstw = (float4*)(Lraw + WI_OFF);
                for (int e = tid; e < 768; e += 256) dstw[e] = srcw[e];
            }
        }
        __syncthreads();   // (D) FF weights (and wi for blk1) visible

        // --- FF from LDS: packed dot + packed axpy ---
        const float* w2L = Lf + 4096;
        #pragma unroll 2
        for (int j = 0; j < 128; ++j) {
            const float* wr = Lf + j * 32;
            f2v h2a = (f2v){0.f, 0.f};
            #pragma unroll
            for (int c2 = 0; c2 < 8; ++c2) {
                float4 wq = *(const float4*)&wr[4 * c2];
                f2v w0; w0[0] = wq.x; w0[1] = wq.y;
                f2v w1v; w1v[0] = wq.z; w1v[1] = wq.w;
                h2a += xn2[2 * c2] * w0;
                h2a += xn2[2 * c2 + 1] * w1v;
            }
            float h = fb1[blk * 128 + j] + h2a[0] + h2a[1];
            h = 0.5f * h * (1.f + erff(h * 0.7071067811865476f));
            f2v hh; hh[0] = h; hh[1] = h;
            const float* w2r = w2L + j * 32;
            #pragma unroll
            for (int c2 = 0; c2 < 8; ++c2) {
                float4 wq = *(const float4*)&w2r[4 * c2];
                f2v w0; w0[0] = wq.x; w0[1] = wq.y;
                f2v w1v; w1v[0] = wq.z; w1v[1] = wq.w;
                t2[2 * c2]     += hh * w0;
                t2[2 * c2 + 1] += hh * w1v;
            }
        }
        {
            const f2v* fb22 = (const f2v*)(fb2 + blk * 32);
            #pragma unroll
            for (int i = 0; i < 16; ++i) t2[i] += fb22[i];
        }
    }

    if (is_tok) {
        float* op = tokens + (size_t)b * 1568 + s * 32;
        #pragma unroll
        for (int i = 0; i < 8; ++i) {
            float4 vv = make_float4(t2[2 * i][0], t2[2 * i][1],
                                    t2[2 * i + 1][0], t2[2 * i + 1][1]);
            *(float4*)&op[4 * i] = vv;
        }
    }
}

// ---------------------------------------------------------------------------
// Pre-split lat_w and memory into fp16 hi/lo pairs AND compute inv_norm
// (merged k_mnorm: block b covers exactly memory row b; identical reduction
// tree -> bit-identical inv_norm).
// ---------------------------------------------------------------------------
__global__ __launch_bounds__(256) void k_split(
    const float* __restrict__ lat_w, const float* __restrict__ memory,
    half_t* __restrict__ lwh, half_t* __restrict__ lwl,
    half_t* __restrict__ memh, half_t* __restrict__ meml,
    float* __restrict__ inv_norm)
{
    __shared__ float red[256];
    const int tid = threadIdx.x;
    size_t i = (size_t)blockIdx.x * 256 + tid;
    if (i < 401408) {   // 256*1568
        float v = lat_w[i];
        half_t h = (half_t)v;
        lwh[i] = h; lwl[i] = (half_t)((v - (float)h) * 2048.0f);
    }
    float v = 0.f;
    if (i < 1048576) {  // 4096*256  (block b == memory row b)
        v = memory[i];
        half_t h = (half_t)v;
        memh[i] = h; meml[i] = (half_t)((v - (float)h) * 2048.0f);
    }
    if (blockIdx.x < 4096) {
        red[tid] = v * v;
        __syncthreads();
        for (int s = 128; s > 0; s >>= 1) {
            if (tid < s) red[tid] += red[tid + s];
            __syncthreads();
        }
        if (tid == 0) inv_norm[blockIdx.x] = 1.f / fmaxf(sqrtf(red[0]), 1e-12f);
    }
}

// ---------------------------------------------------------------------------
// SPLIT-fp16 MFMA GEMM with PRE-SPLIT B: C = A @ B^T (+bias), fp32 out.
// ---------------------------------------------------------------------------
__global__ __launch_bounds__(256) void k_sgemm(
    const float* __restrict__ A, const half_t* __restrict__ Bhg,
    const half_t* __restrict__ Blg, const float* __restrict__ bias,
    float* __restrict__ C, int M, int N, int K)
{
    __shared__ __align__(16) half_t Ah[64 * 40];
    __shared__ __align__(16) half_t Al[64 * 40];
    __shared__ __align__(16) half_t Bh[128 * 40];
    __shared__ __align__(16) half_t Bl[128 * 40];
    const int tid = threadIdx.x;
    const int n0 = blockIdx.x * 128, m0 = blockIdx.y * 64;
    const int w = tid >> 6, lane = tid & 63;
    const int wm = (w >> 1) * 32, wn = (w & 1) * 64;
    const int lr = lane & 15, lk = lane >> 4;

    const int ar = tid >> 2, aseg = (tid & 3) * 8;
    const int br = tid >> 1, bseg = (tid & 1) * 16;

    f4v acch[2][4], accm[2][4];
    #pragma unroll
    for (int i = 0; i < 2; ++i)
        #pragma unroll
        for (int j = 0; j < 4; ++j) {
            acch[i][j] = (f4v){0.f, 0.f, 0.f, 0.f};
            accm[i][j] = (f4v){0.f, 0.f, 0.f, 0.f};
        }

    for (int k0 = 0; k0 < K; k0 += 32) {
        {
            const float* ap = A + (size_t)(m0 + ar) * K + k0 + aseg;
            float4 a0 = *(const float4*)ap;
            float4 a1 = *(const float4*)(ap + 4);
            float av[8] = {a0.x, a0.y, a0.z, a0.w, a1.x, a1.y, a1.z, a1.w};
            h8v ah, al;
            #pragma unroll
            for (int i = 0; i < 8; ++i) {
                half_t h = (half_t)av[i];
                ah[i] = h;
                al[i] = (half_t)((av[i] - (float)h) * 2048.0f);
            }
            *(h8v*)&Ah[ar * 40 + aseg] = ah;
            *(h8v*)&Al[ar * 40 + aseg] = al;

            const half_t* bph = Bhg + (size_t)(n0 + br) * K + k0 + bseg;
            const half_t* bpl = Blg + (size_t)(n0 + br) * K + k0 + bseg;
            h8v bh0 = *(const h8v*)bph;
            h8v bh1 = *(const h8v*)(bph + 8);
            h8v bl0 = *(const h8v*)bpl;
            h8v bl1 = *(const h8v*)(bpl + 8);
            *(h8v*)&Bh[br * 40 + bseg]     = bh0;
            *(h8v*)&Bh[br * 40 + bseg + 8] = bh1;
            *(h8v*)&Bl[br * 40 + bseg]     = bl0;
            *(h8v*)&Bl[br * 40 + bseg + 8] = bl1;
        }
        __syncthreads();
        h8v afh[2], afl[2], bfh[4], bfl[4];
        #pragma unroll
        for (int i = 0; i < 2; ++i) {
            afh[i] = *(const h8v*)&Ah[(wm + i * 16 + lr) * 40 + lk * 8];
            afl[i] = *(const h8v*)&Al[(wm + i * 16 + lr) * 40 + lk * 8];
        }
        #pragma unroll
        for (int j = 0; j < 4; ++j) {
            bfh[j] = *(const h8v*)&Bh[(wn + j * 16 + lr) * 40 + lk * 8];
            bfl[j] = *(const h8v*)&Bl[(wn + j * 16 + lr) * 40 + lk * 8];
        }
        #pragma unroll
        for (int i = 0; i < 2; ++i)
            #pragma unroll
            for (int j = 0; j < 4; ++j) {
                acch[i][j] = __builtin_amdgcn_mfma_f32_16x16x32_f16(afh[i], bfh[j], acch[i][j], 0, 0, 0);
                accm[i][j] = __builtin_amdgcn_mfma_f32_16x16x32_f16(afh[i], bfl[j], accm[i][j], 0, 0, 0);
                accm[i][j] = __builtin_amdgcn_mfma_f32_16x16x32_f16(afl[i], bfh[j], accm[i][j], 0, 0, 0);
            }
        __syncthreads();
    }

    #pragma unroll
    for (int j = 0; j < 4; ++j) {
        int n = n0 + wn + j * 16 + lr;
        float bv = bias ? bias[n] : 0.f;
        #pragma unroll
        for (int i = 0; i < 2; ++i) {
            #pragma unroll
            for (int r = 0; r < 4; ++r) {
                int m = m0 + wm + i * 16 + lk * 4 + r;
                C[(size_t)m * N + n] = acch[i][j][r] + accm[i][j][r] * (1.0f / 2048.0f) + bv;
            }
        }
    }
}

// ---------------------------------------------------------------------------
// MFMA decoder GEMM: d1h[M,N] = (fp16)relu(A[M,K] @ B[N,K]^T + bias).
// ---------------------------------------------------------------------------
__global__ __launch_bounds__(256) void k_dgemm(
    const float* __restrict__ A, const float* __restrict__ Bm,
    const float* __restrict__ bias, half_t* __restrict__ C,
    int M, int N, int K)
{
    __shared__ __align__(16) half_t As[64 * 40];
    __shared__ __align__(16) half_t Bs[128 * 40];
    const int tid = threadIdx.x;
    const int n0 = blockIdx.x * 128, m0 = blockIdx.y * 64;
    const int w = tid >> 6, lane = tid & 63;
    const int wm = (w >> 1) * 32, wn = (w & 1) * 64;
    const int lr = lane & 15, lk = lane >> 4;

    const int ar = tid >> 2, aseg = (tid & 3) * 8;
    const int br = tid >> 1, bseg = (tid & 1) * 16;

    f4v acc[2][4];
    #pragma unroll
    for (int i = 0; i < 2; ++i)
        #pragma unroll
        for (int j = 0; j < 4; ++j) acc[i][j] = (f4v){0.f, 0.f, 0.f, 0.f};

    for (int k0 = 0; k0 < K; k0 += 32) {
        {
            const float* ap = A + (size_t)(m0 + ar) * K + k0 + aseg;
            float4 a0 = *(const float4*)ap;
            float4 a1 = *(const float4*)(ap + 4);
            h8v ha;
            ha[0] = (half_t)a0.x; ha[1] = (half_t)a0.y;
            ha[2] = (half_t)a0.z; ha[3] = (half_t)a0.w;
            ha[4] = (half_t)a1.x; ha[5] = (half_t)a1.y;
            ha[6] = (half_t)a1.z; ha[7] = (half_t)a1.w;
            *(h8v*)&As[ar * 40 + aseg] = ha;

            const float* bp = Bm + (size_t)(n0 + br) * K + k0 + bseg;
            float4 b0 = *(const float4*)bp;
            float4 b1 = *(const float4*)(bp + 4);
            float4 b2 = *(const float4*)(bp + 8);
            float4 b3 = *(const float4*)(bp + 12);
            h8v hb0, hb1;
            hb0[0] = (half_t)b0.x; hb0[1] = (half_t)b0.y;
            hb0[2] = (half_t)b0.z; hb0[3] = (half_t)b0.w;
            hb0[4] = (half_t)b1.x; hb0[5] = (half_t)b1.y;
            hb0[6] = (half_t)b1.z; hb0[7] = (half_t)b1.w;
            hb1[0] = (half_t)b2.x; hb1[1] = (half_t)b2.y;
            hb1[2] = (half_t)b2.z; hb1[3] = (half_t)b2.w;
            hb1[4] = (half_t)b3.x; hb1[5] = (half_t)b3.y;
            hb1[6] = (half_t)b3.z; hb1[7] = (half_t)b3.w;
            *(h8v*)&Bs[br * 40 + bseg] = hb0;
            *(h8v*)&Bs[br * 40 + bseg + 8] = hb1;
        }
        __syncthreads();
        h8v af[2], bfr[4];
        #pragma unroll
        for (int i = 0; i < 2; ++i)
            af[i] = *(const h8v*)&As[(wm + i * 16 + lr) * 40 + lk * 8];
        #pragma unroll
        for (int j = 0; j < 4; ++j)
            bfr[j] = *(const h8v*)&Bs[(wn + j * 16 + lr) * 40 + lk * 8];
        #pragma unroll
        for (int i = 0; i < 2; ++i)
            #pragma unroll
            for (int j = 0; j < 4; ++j)
                acc[i][j] = __builtin_amdgcn_mfma_f32_16x16x32_f16(af[i], bfr[j], acc[i][j], 0, 0, 0);
        __syncthreads();
    }

    #pragma unroll
    for (int j = 0; j < 4; ++j) {
        int n = n0 + wn + j * 16 + lr;
        float bv = bias[n];
        #pragma unroll
        for (int i = 0; i < 2; ++i) {
            #pragma unroll
            for (int r = 0; r < 4; ++r) {
                int m = m0 + wm + i * 16 + lk * 4 + r;
                C[(size_t)m * N + n] = (half_t)fmaxf(acc[i][j][r] + bv, 0.f);
            }
        }
    }
}

// ---------------------------------------------------------------------------
// Fuse dec (linear 256->3136) with convt1. Packed f2v accumulators.
// ---------------------------------------------------------------------------
__global__ __launch_bounds__(256) void k_fuse(
    const float* __restrict__ wt1, const float* __restrict__ upt1_b,
    const float* __restrict__ dec_w, const float* __restrict__ dec_b,
    float* __restrict__ Wf, float* __restrict__ bf)
{
    __shared__ float WL[4][64][32];
    const int p = blockIdx.x;
    const int k = threadIdx.x;
    const int y = p / 14, x = p % 14;

    int ky0 = 0, iy0 = 0, ky1 = 0, iy1 = 0, nky = 0;
    for (int ky = 0; ky < 4; ++ky) {
        int iyn = y + 1 - ky;
        if (iyn < 0 || (iyn & 1)) continue;
        int iy = iyn >> 1;
        if (iy > 6) continue;
        if (nky == 0) { ky0 = ky; iy0 = iy; } else { ky1 = ky; iy1 = iy; }
        ++nky;
    }
    int kx0 = 0, ix0 = 0, kx1 = 0, ix1 = 0, nkx = 0;
    for (int kx = 0; kx < 4; ++kx) {
        int ixn = x + 1 - kx;
        if (ixn < 0 || (ixn & 1)) continue;
        int ix = ixn >> 1;
        if (ix > 6) continue;
        if (nkx == 0) { kx0 = kx; ix0 = ix; } else { kx1 = kx; ix1 = ix; }
        ++nkx;
    }
    const int ntap = nky * nkx;

    for (int e = k; e < ntap * 2048; e += 256) {
        int t = e >> 11, c = (e >> 5) & 63, o = e & 31;
        int ti = (nkx == 2) ? (t >> 1) : t;
        int tj = (nkx == 2) ? (t & 1) : 0;
        int ky = ti ? ky1 : ky0;
        int kx = tj ? kx1 : kx0;
        WL[t][c][o] = wt1[((c * 32 + o) * 4 + ky) * 4 + kx];
    }
    __syncthreads();

    f2v acc2[16];
    #pragma unroll
    for (int o = 0; o < 16; ++o) acc2[o] = (f2v){0.f, 0.f};
    float bacc = 0.f;

    for (int t = 0; t < ntap; ++t) {
        int ti = (nkx == 2) ? (t >> 1) : t;
        int tj = (nkx == 2) ? (t & 1) : 0;
        int iy = ti ? iy1 : iy0;
        int ix = tj ? ix1 : ix0;
        int rbase = iy * 7 + ix;
        for (int c = 0; c < 64; ++c) {
            int row = c * 49 + rbase;
            float v = dec_w[(size_t)row * 256 + k];
            f2v vv; vv[0] = v; vv[1] = v;
            const f2v* w2p = (const f2v*)&WL[t][c][0];
            #pragma unroll
            for (int o2 = 0; o2 < 16; ++o2) acc2[o2] += vv * w2p[o2];
            if (k < 32) bacc = fmaf(WL[t][c][k], dec_b[row], bacc);
        }
    }

    #pragma unroll 4
    for (int o = 0; o < 32; ++o)
        Wf[((size_t)(p * 32 + o)) * 256 + k] = acc2[o >> 1][o & 1];
    if (k < 32) bf[p * 32 + k] = bacc + upt1_b[k];
}

// ---------------------------------------------------------------------------
// Top-k via wave __shfl_xor lexicographic (v,idx) reduce (exactly associative).
// ---------------------------------------------------------------------------
__global__ __launch_bounds__(256) void k_memread(
    const float* __restrict__ latent, const float* __restrict__ dots,
    const float* __restrict__ inv_mn, const float* __restrict__ mem,
    float* __restrict__ out)
{
    __shared__ float red[256];
    __shared__ int   redi[4];
    __shared__ float inv_x_s;
    const int b = blockIdx.x, tid = threadIdx.x;
    const int w = tid >> 6, lane = tid & 63;
    float lx = latent[(size_t)b * 256 + tid];
    red[tid] = lx * lx;
    __syncthreads();
    for (int s = 128; s > 0; s >>= 1) {
        if (tid < s) red[tid] += red[tid + s];
        __syncthreads();
    }
    if (tid == 0) inv_x_s = 1.f / fmaxf(sqrtf(red[0]), 1e-12f);
    __syncthreads();
    const float inv_x = inv_x_s;

    float vals[16];
    for (int j = 0; j < 16; ++j) {
        int m = tid + j * 256;
        vals[j] = dots[(size_t)b * 4096 + m] * inv_mn[m] * inv_x;
    }
    float tv[10]; int ti[10];
    for (int t = 0; t < 10; ++t) {
        float bv = -1e30f; int bidx = 0x7fffffff;
        #pragma unroll
        for (int j = 0; j < 16; ++j) {
            int m = tid + j * 256;
            float v = vals[j];
            if (v > bv || (v == bv && m < bidx)) { bv = v; bidx = m; }
        }
        #pragma unroll
        for (int off = 32; off > 0; off >>= 1) {
            float ov = __shfl_xor(bv, off);
            int   oi = __shfl_xor(bidx, off);
            if (ov > bv || (ov == bv && oi < bidx)) { bv = ov; bidx = oi; }
        }
        if (lane == 0) { red[w] = bv; redi[w] = bidx; }
        __syncthreads();
        float fv = red[0]; int fi = redi[0];
        #pragma unroll
        for (int q = 1; q < 4; ++q) {
            float v2 = red[q]; int i2 = redi[q];
            if (v2 > fv || (v2 == fv && i2 < fi)) { fv = v2; fi = i2; }
        }
        tv[t] = fv; ti[t] = fi;
        if ((fi & 255) == tid) vals[fi >> 8] = -1e30f;
        __syncthreads();
    }
    float wgt[10], wsum = 0.f;
    for (int t = 0; t < 10; ++t) { wgt[t] = expf(tv[t] - tv[0]); wsum += wgt[t]; }
    float inv_ws = 1.f / wsum;
    float acc = 0.f;
    for (int t = 0; t < 10; ++t) acc += (wgt[t] * inv_ws) * mem[(size_t)ti[t] * 256 + tid];
    out[(size_t)b * 256 + tid] = acc;
}

// ---------------------------------------------------------------------------
// Weight repack.
// ---------------------------------------------------------------------------
__global__ __launch_bounds__(256) void k_pack(
    const float* __restrict__ wc1, const float* __restrict__ wt2,
    const float* __restrict__ wc2, const float* __restrict__ w2src,
    half_t* __restrict__ pk2h, half_t* __restrict__ pk3h,
    float* __restrict__ pk4, float* __restrict__ pk5)
{
    int i = blockIdx.x * 256 + threadIdx.x;
    if (i < 9216) {
        int ic = i & 31, oc = (i >> 5) & 15, nt = (i >> 9) & 1, t = i >> 10;
        pk2h[i] = (half_t)wc1[((nt * 16 + oc) * 32 + ic) * 9 + t];
    }
    if (i < 8192) {
        int ic = i & 31, oc = (i >> 5) & 15, t = (i >> 9) & 3, q = i >> 11;
        int wy = t >> 1, wx = t & 1, py = q >> 1, px = q & 1;
        int ky = 3 - py - 2 * wy, kx = 3 - px - 2 * wx;
        pk3h[i] = (half_t)wt2[((ic * 16 + oc) * 4 + ky) * 4 + kx];
    }
    if (i < 1152) {
        int o = i & 7, tap = (i >> 3) % 9, c = i / 72;
        pk4[i] = wc2[(o * 16 + c) * 9 + tap];
    }
    if (i < 8192) {
        int c = i & 31, j = (i >> 5) & 127, bq = i >> 12;
        pk5[i] = w2src[bq * 4096 + c * 128 + j];
    }
}

// ---------------------------------------------------------------------------
// Conv2d 32->32 k3 p1, 14x14, ReLU — MFMA. 2 samples/block.
// ---------------------------------------------------------------------------
__global__ __launch_bounds__(256) void k_conv1(
    const half_t* __restrict__ in, const half_t* __restrict__ wh,
    const float* __restrict__ bias, half_t* __restrict__ out)
{
    __shared__ __align__(16) half_t P[2 * 16 * 16 * 40];
    const int tid = threadIdx.x;
    const int w = tid >> 6, lane = tid & 63;
    const size_t b0 = (size_t)blockIdx.x * 2;

    for (int e = tid; e < 10240; e += 256) ((unsigned int*)P)[e] = 0u;
    __syncthreads();
    {
        const unsigned int* src = (const unsigned int*)in;
        for (int e = tid; e < 6272; e += 256) {
            int si = e / 3136;
            int rem = e - si * 3136;
            int p = rem >> 4, c2 = rem & 15;
            int y = p / 14, x = p % 14;
            ((unsigned int*)P)[si * 5120 + ((y + 1) * 16 + (x + 1)) * 20 + c2] =
                src[(b0 + si) * 3136 + rem];
        }
    }

    h8v bfr[9][2];
    #pragma unroll
    for (int t = 0; t < 9; ++t)
        #pragma unroll
        for (int nt = 0; nt < 2; ++nt)
            bfr[t][nt] = *(const h8v*)&wh[((size_t)((t * 2 + nt) * 16 + (lane & 15))) * 32 + (lane >> 4) * 8];

    __syncthreads();

    const int kseg = (lane >> 4) * 8;
    const int oc = lane & 15;
    const float bv0 = bias[oc], bv1 = bias[16 + oc];

    for (int job = w; job < 26; job += 4) {
        const int si = job >= 13 ? 1 : 0;
        const int tile = job - si * 13;
        int p = tile * 16 + (lane & 15);
        if (p > 195) p = 195;
        const int y = p / 14, x = p % 14;
        const half_t* Pb = P + si * 10240;

        f4v acc0 = (f4v){0.f, 0.f, 0.f, 0.f};
        f4v acc1 = (f4v){0.f, 0.f, 0.f, 0.f};
        #pragma unroll
        for (int ky = 0; ky < 3; ++ky) {
            #pragma unroll
            for (int kx = 0; kx < 3; ++kx) {
                h8v af = *(const h8v*)&Pb[((y + ky) * 16 + (x + kx)) * 40 + kseg];
                acc0 = __builtin_amdgcn_mfma_f32_16x16x32_f16(af, bfr[ky * 3 + kx][0], acc0, 0, 0, 0);
                acc1 = __builtin_amdgcn_mfma_f32_16x16x32_f16(af, bfr[ky * 3 + kx][1], acc1, 0, 0, 0);
            }
        }

        const int pr0 = tile * 16 + (lane >> 4) * 4;
        half_t* ob = out + (b0 + si) * 6272;
        #pragma unroll
        for (int r = 0; r < 4; ++r) {
            int pp = pr0 + r;
            if (pp < 196) {
                ob[(size_t)pp * 32 + oc]      = (half_t)fmaxf(acc0[r] + bv0, 0.f);
                ob[(size_t)pp * 32 + 16 + oc] = (half_t)fmaxf(acc1[r] + bv1, 0.f);
            }
        }
    }
}

// ---------------------------------------------------------------------------
// FUSED: ConvTranspose2d 32->16 k4 s2 p1 (MFMA) + Conv2d 16->8 k3 p1 (ReLU,
// packed f2v) + Conv2d 8->1 k1. One sample/block.
// ---------------------------------------------------------------------------
__global__ __launch_bounds__(256) void k_convt23(
    const half_t* __restrict__ in, const half_t* __restrict__ pk3h,
    const float* __restrict__ bt2, const float* __restrict__ pk4,
    const float* __restrict__ b2, const float* __restrict__ w3,
    const float* __restrict__ b3, float* __restrict__ out)
{
    __shared__ __align__(16) unsigned char Lraw[30720];
    half_t* Pin = (half_t*)Lraw;
    float*  P2  = (float*)Lraw;
    const int tid = threadIdx.x;
    const int w = tid >> 6, lane = tid & 63;
    const int b = blockIdx.x;

    for (int e = tid; e < 5120; e += 256) ((unsigned int*)Pin)[e] = 0u;
    __syncthreads();
    {
        const unsigned int* src = (const unsigned int*)in;
        for (int e = tid; e < 3136; e += 256) {
            int p = e >> 4, c2 = e & 15;
            int y = p / 14, x = p % 14;
            ((unsigned int*)Pin)[((y + 1) * 16 + (x + 1)) * 20 + c2] =
                src[(size_t)b * 3136 + e];
        }
    }
    __syncthreads();

    const int oc = lane & 15;
    const int kseg = (lane >> 4) * 8;

    f4v res[13];
    #pragma unroll
    for (int j = 0; j < 13; ++j) {
        const int job = w + 4 * j;
        const int q = job / 13, tile = job - q * 13;
        const int py = q >> 1, px = q & 1;
        int p = tile * 16 + (lane & 15);
        if (p > 195) p = 195;
        const int ty = p / 14, tx = p % 14;
        f4v a = (f4v){0.f, 0.f, 0.f, 0.f};
        #pragma unroll
        for (int t = 0; t < 4; ++t) {
            const int wy = t >> 1, wx = t & 1;
            h8v bf = *(const h8v*)&pk3h[((size_t)((q * 4 + t) * 16 + oc)) * 32 + kseg];
            h8v af = *(const h8v*)&Pin[((ty + py + wy) * 16 + (tx + px + wx)) * 40 + kseg];
            a = __builtin_amdgcn_mfma_f32_16x16x32_f16(af, bf, a, 0, 0, 0);
        }
        res[j] = a;
    }
    __syncthreads();

    const bool active2 = tid < 196;
    int row = active2 ? tid / 7 : 0;
    int tx0b = active2 ? (tid % 7) * 4 : 0;
    const float bco = bt2[oc];

    f2v acc2[4][4];
    #pragma unroll
    for (int i = 0; i < 4; ++i)
        #pragma unroll
        for (int o2 = 0; o2 < 4; ++o2) acc2[i][o2] = (f2v){0.f, 0.f};

    #pragma unroll
    for (int g = 0; g < 2; ++g) {
        for (int e = tid; e < 7680; e += 256) P2[e] = 0.f;
        __syncthreads();
        if ((oc >> 3) == g) {
            #pragma unroll
            for (int j = 0; j < 13; ++j) {
                const int job = w + 4 * j;
                const int q = job / 13, tile = job - q * 13;
                const int py = q >> 1, px = q & 1;
                const int pr0 = tile * 16 + (lane >> 4) * 4;
                #pragma unroll
                for (int r = 0; r < 4; ++r) {
                    int p = pr0 + r;
                    if (p < 196) {
                        int Y = 2 * (p / 14) + py, X = 2 * (p % 14) + px;
                        P2[((oc & 7) * 30 + Y + 1) * 32 + (X + 1)] = fmaxf(res[j][r] + bco, 0.f);
                    }
                }
            }
        }
        __syncthreads();
        for (int cl = 0; cl < 8; ++cl) {
            const float* Pb = &P2[(cl * 30 + row) * 32 + tx0b];
            const float* wb = pk4 + (size_t)(g * 8 + cl) * 72;
            #pragma unroll
            for (int ky = 0; ky < 3; ++ky) {
                float4 a = *(const float4*)&Pb[ky * 32];
                float4 bq = *(const float4*)&Pb[ky * 32 + 4];
                float rowb[8] = {a.x, a.y, a.z, a.w, bq.x, bq.y, bq.z, bq.w};
                #pragma unroll
                for (int kx = 0; kx < 3; ++kx) {
                    const f2v* wt2p = (const f2v*)(wb + (ky * 3 + kx) * 8);
                    #pragma unroll
                    for (int i = 0; i < 4; ++i) {
                        f2v rb; rb[0] = rowb[i + kx]; rb[1] = rowb[i + kx];
                        acc2[i][0] += rb * wt2p[0];
                        acc2[i][1] += rb * wt2p[1];
                        acc2[i][2] += rb * wt2p[2];
                        acc2[i][3] += rb * wt2p[3];
                    }
                }
            }
        }
        __syncthreads();
    }

    if (active2) {
        const float bias3 = b3[0];
        #pragma unroll
        for (int i = 0; i < 4; ++i) {
            float r = bias3;
            #pragma unroll
            for (int o = 0; o < 8; ++o)
                r += fmaxf(acc2[i][o >> 1][o & 1] + b2[o], 0.f) * w3[o];
            out[(size_t)b * 784 + row * 28 + tx0b + i] = r;
        }
    }
}

// ---------------------------------------------------------------------------
extern "C" void kernel_launch(void* const* d_in, const int* in_sizes, int n_in,
                              void* d_out, int out_size, void* d_ws, size_t ws_size,
                              hipStream_t stream)
{
    const float* x       = (const float*)d_in[0];
    const float* patch_w = (const float*)d_in[1];
    const float* patch_b = (const float*)d_in[2];
    const float* ln1g    = (const float*)d_in[3];
    const float* ln1b    = (const float*)d_in[4];
    const float* wi      = (const float*)d_in[5];
    const float* bi      = (const float*)d_in[6];
    const float* wo      = (const float*)d_in[7];
    const float* bo      = (const float*)d_in[8];
    const float* ln2g    = (const float*)d_in[9];
    const float* ln2b    = (const float*)d_in[10];
    const float* w1      = (const float*)d_in[11];
    const float* b1      = (const float*)d_in[12];
    const float* w2      = (const float*)d_in[13];
    const float* b2      = (const float*)d_in[14];
    const float* lat_w   = (const float*)d_in[15];
    const float* lat_b   = (const float*)d_in[16];
    const float* memory  = (const float*)d_in[17];
    const float* dec_w   = (const float*)d_in[18];
    const float* dec_b   = (const float*)d_in[19];
    const float* upt1_w  = (const float*)d_in[20];
    const float* upt1_b  = (const float*)d_in[21];
    const float* c1_w    = (const float*)d_in[22];
    const float* c1_b    = (const float*)d_in[23];
    const float* upt2_w  = (const float*)d_in[24];
    const float* upt2_b  = (const float*)d_in[25];
    const float* c2_w    = (const float*)d_in[26];
    const float* c2_b    = (const float*)d_in[27];
    const float* c3_w    = (const float*)d_in[28];
    const float* c3_b    = (const float*)d_in[29];
    float* outp = (float*)d_out;

    float* ws = (float*)d_ws;
    size_t off = 0;
    auto alloc = [&](size_t n) { float* p = ws + off; off += (n + 63) & ~(size_t)63; return p; };
    float* tokens     = alloc((size_t)B_TOT * 1568);
    float* latent     = alloc((size_t)B_TOT * 256);
    float* dots       = alloc((size_t)B_TOT * 4096);
    float* mem_latent = alloc((size_t)B_TOT * 256);
    float* inv_mn     = alloc(4096);
    half_t* pk2h      = (half_t*)alloc(4608);
    half_t* pk3h      = (half_t*)alloc(4096);
    float* pk4        = alloc(1152);
    float* pk5        = alloc(8192);
    float* Wf         = alloc((size_t)6272 * 256);
    float* bf         = alloc(6272);
    half_t* d1h       = (half_t*)alloc((size_t)CHUNK * 6272 / 2);
    half_t* d2h       = (half_t*)alloc((size_t)CHUNK * 6272 / 2);
    half_t* lwh       = (half_t*)alloc(200704);   // 256*1568 halves
    half_t* lwl       = (half_t*)alloc(200704);
    half_t* memh      = (half_t*)alloc(524288);   // 4096*256 halves
    half_t* meml      = (half_t*)alloc(524288);
    (void)in_sizes; (void)n_in; (void)out_size; (void)ws_size;

    // Prep: repack, pre-split GEMM B operands (+inv_norm), dec/convt1 fusion
    k_pack<<<36, 256, 0, stream>>>(c1_w, upt2_w, c2_w, w2, pk2h, pk3h, pk4, pk5);
    k_split<<<4096, 256, 0, stream>>>(lat_w, memory, lwh, lwl, memh, meml, inv_mn);
    k_fuse<<<196, 256, 0, stream>>>(upt1_w, upt1_b, dec_w, dec_b, Wf, bf);

    // Encoder (wave-per-sample, packed fp32 math)
    k_tokens<<<B_TOT / 4, 256, 0, stream>>>(x, patch_w, patch_b, ln1g, ln1b, wi, bi,
                                            wo, bo, ln2g, ln2b, w1, b1, pk5, b2, tokens);
    // latent + dots via split-fp16 MFMA with pre-split B
    k_sgemm<<<dim3(256 / 128, B_TOT / 64), 256, 0, stream>>>(tokens, lwh, lwl, lat_b,
                                                             latent, B_TOT, 256, 1568);
    k_sgemm<<<dim3(4096 / 128, B_TOT / 64), 256, 0, stream>>>(latent, memh, meml, nullptr,
                                                              dots, B_TOT, 4096, 256);
    k_memread<<<B_TOT, 256, 0, stream>>>(latent, dots, inv_mn, memory, mem_latent);

    // Decoder, full batch in one pass.
    for (int c = 0; c < B_TOT / CHUNK; ++c) {
        const float* ml = mem_latent + (size_t)c * CHUNK * 256;
        k_dgemm<<<dim3(6272 / 128, CHUNK / 64), 256, 0, stream>>>(ml, Wf, bf, d1h,
                                                                  CHUNK, 6272, 256);
        k_conv1  <<<CHUNK / 2, 256, 0, stream>>>(d1h, pk2h, c1_b, d2h);
        k_convt23<<<CHUNK, 256, 0, stream>>>(d2h, pk3h, upt2_b, pk4, c2_b, c3_w, c3_b,
                                             outp + (size_t)c * CHUNK * 784);
    }
}

// Round 19
// 1014.614 us; speedup vs baseline: 1.0990x; 1.0266x over previous
//
#include <hip/hip_runtime.h>
#include <math.h>

#define B_TOT 4096
#define CHUNK 4096

typedef _Float16 half_t;
typedef _Float16 h2 __attribute__((ext_vector_type(2)));
typedef _Float16 h8v __attribute__((ext_vector_type(8)));
typedef float f4v __attribute__((ext_vector_type(4)));
typedef float f2v __attribute__((ext_vector_type(2)));

#if __has_builtin(__builtin_amdgcn_fdot2)
#define FDOT2(a, b, c) __builtin_amdgcn_fdot2((a), (b), (c), false)
#else
#define FDOT2(a, b, c) fmaf((float)(a)[1], (float)(b)[1], fmaf((float)(a)[0], (float)(b)[0], (c)))
#endif

// Base: round-18 (1041.6us). This round: k_conv1 + k_convt23 FUSED into
// k_c123 (1 sample/block). conv1's ReLU'd fp16 output goes to LDS region B
// (same fp16 quantization as the old d2h HBM round-trip -> bit-identical),
// eliminating 51MB of HBM traffic + a launch + a re-staging pass.
// LDS: A=[16][16][40]h input (20480) + B=[16][16][40]h conv1-out (20480)
// = 40960 -> 4 blocks/CU; conv2's fp32 [8][30][32] (30720) overlays A+B
// after both are dead. k_tokens settled (427us, wi-in-LDS, r17 closed).
// V fp32 (r4); latent/dots split-fp16 MFMA (r14-16); decoder fp16 MFMA.
#define KSTR 36
#define VSTR 34
#define KBYTES (49 * 72)
#define WAVE_LDS (49 * 72 + 49 * 136)  // 10192
#define WI_OFF  (4 * WAVE_LDS)         // 40768
#define BLOCK_LDS (WI_OFF + 12288)     // 53056

// ---------------------------------------------------------------------------
// Fused: patch conv (1->32, k4 s4) + 2 transformer blocks. Packed-fp32 math.
// ---------------------------------------------------------------------------
__global__ __launch_bounds__(256) void k_tokens(
    const float* __restrict__ x, const float* __restrict__ pw, const float* __restrict__ pb,
    const float* __restrict__ ln1g, const float* __restrict__ ln1b,
    const float* __restrict__ wi, const float* __restrict__ bi,
    const float* __restrict__ wo, const float* __restrict__ bo,
    const float* __restrict__ ln2g, const float* __restrict__ ln2b,
    const float* __restrict__ w1, const float* __restrict__ fb1,
    const float* __restrict__ w2t, const float* __restrict__ fb2,
    float* __restrict__ tokens)
{
    __shared__ __align__(16) unsigned char Lraw[BLOCK_LDS];
    const int tid = threadIdx.x;
    const int wv = tid >> 6, lane = tid & 63;
    const int b = blockIdx.x * 4 + wv;
    half_t* Kb = (half_t*)(Lraw + wv * WAVE_LDS);
    float*  Vb = (float*)(Lraw + wv * WAVE_LDS + KBYTES);
    const float* wiL = (const float*)(Lraw + WI_OFF);
    float* Lf = (float*)Lraw;            // FF-weight overlay (block-wide)
    const bool is_tok = lane < 49;
    const int s = is_tok ? lane : 48;
    const int py = s / 7, px = s % 7;

    // --- prologue: stage blk-0 qkv weights (visible after barrier (A)) ---
    {
        const float4* srcw = (const float4*)(wi);
        float4* dstw = (float4*)(Lraw + WI_OFF);
        for (int e = tid; e < 768; e += 256) dstw[e] = srcw[e];
    }

    // --- patch conv: direct float4 loads; packed accumulate ---
    f2v xv2[8];
    const float* xb = x + (size_t)b * 784 + py * 112 + px * 4;
    #pragma unroll
    for (int r = 0; r < 4; ++r) {
        float4 vq = *(const float4*)(xb + r * 28);
        f2v lo; lo[0] = vq.x; lo[1] = vq.y;
        f2v hi; hi[0] = vq.z; hi[1] = vq.w;
        xv2[2 * r] = lo; xv2[2 * r + 1] = hi;
    }
    f2v t2[16];
    #pragma unroll
    for (int c = 0; c < 32; ++c) {
        const float* wr = pw + c * 16;
        f2v a2 = (f2v){0.f, 0.f};
        #pragma unroll
        for (int c2 = 0; c2 < 4; ++c2) {
            float4 wq = *(const float4*)&wr[4 * c2];
            f2v w0; w0[0] = wq.x; w0[1] = wq.y;
            f2v w1v; w1v[0] = wq.z; w1v[1] = wq.w;
            a2 += xv2[2 * c2] * w0;
            a2 += xv2[2 * c2 + 1] * w1v;
        }
        t2[c >> 1][c & 1] = pb[c] + a2[0] + a2[1];
    }

    for (int blk = 0; blk < 2; ++blk) {
        const float* bib = bi + blk * 96;

        // --- LN1 ---
        f2v mu2 = (f2v){0.f, 0.f};
        #pragma unroll
        for (int i = 0; i < 16; ++i) mu2 += t2[i];
        float mu = (mu2[0] + mu2[1]) * 0.03125f;
        f2v mub; mub[0] = mu; mub[1] = mu;
        f2v var2 = (f2v){0.f, 0.f};
        #pragma unroll
        for (int i = 0; i < 16; ++i) { f2v d = t2[i] - mub; var2 += d * d; }
        float rstd = rsqrtf((var2[0] + var2[1]) * 0.03125f + 1e-5f);
        f2v rstd2; rstd2[0] = rstd; rstd2[1] = rstd;
        f2v xn2[16];
        {
            const f2v* g2 = (const f2v*)(ln1g + blk * 32);
            const f2v* bl2 = (const f2v*)(ln1b + blk * 32);
            #pragma unroll
            for (int i = 0; i < 16; ++i)
                xn2[i] = (t2[i] - mub) * rstd2 * g2[i] + bl2[i];
        }

        __syncthreads();   // (A) prior-phase LDS reads done; wi stage visible

        // --- K projection -> LDS fp16 ---
        #pragma unroll 4
        for (int d = 0; d < 32; ++d) {
            const float* wr = wiL + (32 + d) * 32;
            f2v a2 = (f2v){0.f, 0.f};
            #pragma unroll
            for (int c2 = 0; c2 < 8; ++c2) {
                float4 wq = *(const float4*)&wr[4 * c2];
                f2v w0; w0[0] = wq.x; w0[1] = wq.y;
                f2v w1v; w1v[0] = wq.z; w1v[1] = wq.w;
                a2 += xn2[2 * c2] * w0;
                a2 += xn2[2 * c2 + 1] * w1v;
            }
            if (is_tok) Kb[s * KSTR + d] = (half_t)(bib[32 + d] + a2[0] + a2[1]);
        }
        // --- V projection -> LDS fp32 ---
        #pragma unroll 4
        for (int d = 0; d < 32; ++d) {
            const float* wr = wiL + (64 + d) * 32;
            f2v a2 = (f2v){0.f, 0.f};
            #pragma unroll
            for (int c2 = 0; c2 < 8; ++c2) {
                float4 wq = *(const float4*)&wr[4 * c2];
                f2v w0; w0[0] = wq.x; w0[1] = wq.y;
                f2v w1v; w1v[0] = wq.z; w1v[1] = wq.w;
                a2 += xn2[2 * c2] * w0;
                a2 += xn2[2 * c2 + 1] * w1v;
            }
            if (is_tok) Vb[s * VSTR + d] = bib[64 + d] + a2[0] + a2[1];
        }
        // --- Q projection (scaled) ---
        float q0[32];
        #pragma unroll 4
        for (int d = 0; d < 32; ++d) {
            const float* wr = wiL + d * 32;
            f2v a2 = (f2v){0.f, 0.f};
            #pragma unroll
            for (int c2 = 0; c2 < 8; ++c2) {
                float4 wq = *(const float4*)&wr[4 * c2];
                f2v w0; w0[0] = wq.x; w0[1] = wq.y;
                f2v w1v; w1v[0] = wq.z; w1v[1] = wq.w;
                a2 += xn2[2 * c2] * w0;
                a2 += xn2[2 * c2 + 1] * w1v;
            }
            q0[d] = (bib[d] + a2[0] + a2[1]) * 0.25f;
        }
        h2 qh[16];
        #pragma unroll
        for (int i = 0; i < 16; ++i) {
            h2 hh; hh[0] = (half_t)q0[2 * i]; hh[1] = (half_t)q0[2 * i + 1];
            qh[i] = hh;
        }

        // wave-local fence: own K/V ds_writes visible before broadcast reads
        __asm__ volatile("s_waitcnt lgkmcnt(0)" ::: "memory");

        // --- attention: 2 heads of 16 dims; packed PV ---
        f2v o2[16];
        #pragma unroll
        for (int i = 0; i < 16; ++i) o2[i] = (f2v){0.f, 0.f};
        float l0 = 0.f, l1 = 0.f;
        union H4 { double qd; h2 p[2]; };
        for (int j = 0; j < 49; ++j) {
            const double* kr = (const double*)(Kb + j * KSTR);
            const float* vr = Vb + j * VSTR;
            H4 u0, u1, u2, u3, w0, w1h, w2h, w3;
            u0.qd = kr[0]; u1.qd = kr[1]; u2.qd = kr[2]; u3.qd = kr[3];
            w0.qd = kr[4]; w1h.qd = kr[5]; w2h.qd = kr[6]; w3.qd = kr[7];
            float s0a = 0.f, s0b = 0.f, s1a = 0.f, s1b = 0.f;
            s0a = FDOT2(u0.p[0], qh[0], s0a); s0a = FDOT2(u0.p[1], qh[1], s0a);
            s0b = FDOT2(u1.p[0], qh[2], s0b); s0b = FDOT2(u1.p[1], qh[3], s0b);
            s0a = FDOT2(u2.p[0], qh[4], s0a); s0a = FDOT2(u2.p[1], qh[5], s0a);
            s0b = FDOT2(u3.p[0], qh[6], s0b); s0b = FDOT2(u3.p[1], qh[7], s0b);
            s1a = FDOT2(w0.p[0], qh[8], s1a); s1a = FDOT2(w0.p[1], qh[9], s1a);
            s1b = FDOT2(w1h.p[0], qh[10], s1b); s1b = FDOT2(w1h.p[1], qh[11], s1b);
            s1a = FDOT2(w2h.p[0], qh[12], s1a); s1a = FDOT2(w2h.p[1], qh[13], s1a);
            s1b = FDOT2(w3.p[0], qh[14], s1b); s1b = FDOT2(w3.p[1], qh[15], s1b);
            float p0 = __expf(s0a + s0b), p1 = __expf(s1a + s1b);
            l0 += p0; l1 += p1;
            f2v p02; p02[0] = p0; p02[1] = p0;
            f2v p12; p12[0] = p1; p12[1] = p1;
            #pragma unroll
            for (int i = 0; i < 8; ++i) {
                f2v va = *(const f2v*)&vr[2 * i];
                o2[i] += p02 * va;
                f2v vc = *(const f2v*)&vr[16 + 2 * i];
                o2[8 + i] += p12 * vc;
            }
        }
        {
            float il0 = 1.f / l0, il1 = 1.f / l1;
            f2v il02; il02[0] = il0; il02[1] = il0;
            f2v il12; il12[0] = il1; il12[1] = il1;
            #pragma unroll
            for (int i = 0; i < 8; ++i) { o2[i] *= il02; o2[8 + i] *= il12; }
        }

        // --- out projection + residual ---
        #pragma unroll
        for (int c = 0; c < 32; ++c) {
            const float* wr = wo + blk * 1024 + c * 32;
            f2v a2 = (f2v){0.f, 0.f};
            #pragma unroll
            for (int c2 = 0; c2 < 8; ++c2) {
                float4 wq = *(const float4*)&wr[4 * c2];
                f2v w0; w0[0] = wq.x; w0[1] = wq.y;
                f2v w1v; w1v[0] = wq.z; w1v[1] = wq.w;
                a2 += o2[2 * c2] * w0;
                a2 += o2[2 * c2 + 1] * w1v;
            }
            t2[c >> 1][c & 1] += bo[blk * 32 + c] + a2[0] + a2[1];
        }

        // --- LN2 ---
        mu2 = (f2v){0.f, 0.f};
        #pragma unroll
        for (int i = 0; i < 16; ++i) mu2 += t2[i];
        mu = (mu2[0] + mu2[1]) * 0.03125f;
        mub[0] = mu; mub[1] = mu;
        var2 = (f2v){0.f, 0.f};
        #pragma unroll
        for (int i = 0; i < 16; ++i) { f2v d = t2[i] - mub; var2 += d * d; }
        rstd = rsqrtf((var2[0] + var2[1]) * 0.03125f + 1e-5f);
        rstd2[0] = rstd; rstd2[1] = rstd;
        {
            const f2v* g2 = (const f2v*)(ln2g + blk * 32);
            const f2v* bl2 = (const f2v*)(ln2b + blk * 32);
            #pragma unroll
            for (int i = 0; i < 16; ++i)
                xn2[i] = (t2[i] - mub) * rstd2 * g2[i] + bl2[i];
        }

        __syncthreads();   // (C) all waves done reading K/V + wi

        // --- stage FF weights (overlay over KV) + next blk's wi ---
        {
            const float4* src1 = (const float4*)(w1 + blk * 4096);
            const float4* src2 = (const float4*)(w2t + blk * 4096);
            float4* dst = (float4*)Lraw;
            for (int e = tid; e < 1024; e += 256) dst[e] = src1[e];
            for (int e = tid; e < 1024; e += 256) dst[1024 + e] = src2[e];
            if (blk == 0) {
                const float4* srcw = (const float4*)(wi + 3072);
                float4* dstw = (float4*)(Lraw + WI_OFF);
                for (int e = tid; e < 768; e += 256) dstw[e] = srcw[e];
            }
        }
        __syncthreads();   // (D) FF weights (and wi for blk1) visible

        // --- FF from LDS: packed dot + packed axpy ---
        const float* w2L = Lf + 4096;
        #pragma unroll 2
        for (int j = 0; j < 128; ++j) {
            const float* wr = Lf + j * 32;
            f2v h2a = (f2v){0.f, 0.f};
            #pragma unroll
            for (int c2 = 0; c2 < 8; ++c2) {
                float4 wq = *(const float4*)&wr[4 * c2];
                f2v w0; w0[0] = wq.x; w0[1] = wq.y;
                f2v w1v; w1v[0] = wq.z; w1v[1] = wq.w;
                h2a += xn2[2 * c2] * w0;
                h2a += xn2[2 * c2 + 1] * w1v;
            }
            float h = fb1[blk * 128 + j] + h2a[0] + h2a[1];
            h = 0.5f * h * (1.f + erff(h * 0.7071067811865476f));
            f2v hh; hh[0] = h; hh[1] = h;
            const float* w2r = w2L + j * 32;
            #pragma unroll
            for (int c2 = 0; c2 < 8; ++c2) {
                float4 wq = *(const float4*)&w2r[4 * c2];
                f2v w0; w0[0] = wq.x; w0[1] = wq.y;
                f2v w1v; w1v[0] = wq.z; w1v[1] = wq.w;
                t2[2 * c2]     += hh * w0;
                t2[2 * c2 + 1] += hh * w1v;
            }
        }
        {
            const f2v* fb22 = (const f2v*)(fb2 + blk * 32);
            #pragma unroll
            for (int i = 0; i < 16; ++i) t2[i] += fb22[i];
        }
    }

    if (is_tok) {
        float* op = tokens + (size_t)b * 1568 + s * 32;
        #pragma unroll
        for (int i = 0; i < 8; ++i) {
            float4 vv = make_float4(t2[2 * i][0], t2[2 * i][1],
                                    t2[2 * i + 1][0], t2[2 * i + 1][1]);
            *(float4*)&op[4 * i] = vv;
        }
    }
}

// ---------------------------------------------------------------------------
// Pre-split lat_w and memory into fp16 hi/lo pairs AND compute inv_norm.
// ---------------------------------------------------------------------------
__global__ __launch_bounds__(256) void k_split(
    const float* __restrict__ lat_w, const float* __restrict__ memory,
    half_t* __restrict__ lwh, half_t* __restrict__ lwl,
    half_t* __restrict__ memh, half_t* __restrict__ meml,
    float* __restrict__ inv_norm)
{
    __shared__ float red[256];
    const int tid = threadIdx.x;
    size_t i = (size_t)blockIdx.x * 256 + tid;
    if (i < 401408) {   // 256*1568
        float v = lat_w[i];
        half_t h = (half_t)v;
        lwh[i] = h; lwl[i] = (half_t)((v - (float)h) * 2048.0f);
    }
    float v = 0.f;
    if (i < 1048576) {  // 4096*256  (block b == memory row b)
        v = memory[i];
        half_t h = (half_t)v;
        memh[i] = h; meml[i] = (half_t)((v - (float)h) * 2048.0f);
    }
    if (blockIdx.x < 4096) {
        red[tid] = v * v;
        __syncthreads();
        for (int s = 128; s > 0; s >>= 1) {
            if (tid < s) red[tid] += red[tid + s];
            __syncthreads();
        }
        if (tid == 0) inv_norm[blockIdx.x] = 1.f / fmaxf(sqrtf(red[0]), 1e-12f);
    }
}

// ---------------------------------------------------------------------------
// SPLIT-fp16 MFMA GEMM with PRE-SPLIT B: C = A @ B^T (+bias), fp32 out.
// ---------------------------------------------------------------------------
__global__ __launch_bounds__(256) void k_sgemm(
    const float* __restrict__ A, const half_t* __restrict__ Bhg,
    const half_t* __restrict__ Blg, const float* __restrict__ bias,
    float* __restrict__ C, int M, int N, int K)
{
    __shared__ __align__(16) half_t Ah[64 * 40];
    __shared__ __align__(16) half_t Al[64 * 40];
    __shared__ __align__(16) half_t Bh[128 * 40];
    __shared__ __align__(16) half_t Bl[128 * 40];
    const int tid = threadIdx.x;
    const int n0 = blockIdx.x * 128, m0 = blockIdx.y * 64;
    const int w = tid >> 6, lane = tid & 63;
    const int wm = (w >> 1) * 32, wn = (w & 1) * 64;
    const int lr = lane & 15, lk = lane >> 4;

    const int ar = tid >> 2, aseg = (tid & 3) * 8;
    const int br = tid >> 1, bseg = (tid & 1) * 16;

    f4v acch[2][4], accm[2][4];
    #pragma unroll
    for (int i = 0; i < 2; ++i)
        #pragma unroll
        for (int j = 0; j < 4; ++j) {
            acch[i][j] = (f4v){0.f, 0.f, 0.f, 0.f};
            accm[i][j] = (f4v){0.f, 0.f, 0.f, 0.f};
        }

    for (int k0 = 0; k0 < K; k0 += 32) {
        {
            const float* ap = A + (size_t)(m0 + ar) * K + k0 + aseg;
            float4 a0 = *(const float4*)ap;
            float4 a1 = *(const float4*)(ap + 4);
            float av[8] = {a0.x, a0.y, a0.z, a0.w, a1.x, a1.y, a1.z, a1.w};
            h8v ah, al;
            #pragma unroll
            for (int i = 0; i < 8; ++i) {
                half_t h = (half_t)av[i];
                ah[i] = h;
                al[i] = (half_t)((av[i] - (float)h) * 2048.0f);
            }
            *(h8v*)&Ah[ar * 40 + aseg] = ah;
            *(h8v*)&Al[ar * 40 + aseg] = al;

            const half_t* bph = Bhg + (size_t)(n0 + br) * K + k0 + bseg;
            const half_t* bpl = Blg + (size_t)(n0 + br) * K + k0 + bseg;
            h8v bh0 = *(const h8v*)bph;
            h8v bh1 = *(const h8v*)(bph + 8);
            h8v bl0 = *(const h8v*)bpl;
            h8v bl1 = *(const h8v*)(bpl + 8);
            *(h8v*)&Bh[br * 40 + bseg]     = bh0;
            *(h8v*)&Bh[br * 40 + bseg + 8] = bh1;
            *(h8v*)&Bl[br * 40 + bseg]     = bl0;
            *(h8v*)&Bl[br * 40 + bseg + 8] = bl1;
        }
        __syncthreads();
        h8v afh[2], afl[2], bfh[4], bfl[4];
        #pragma unroll
        for (int i = 0; i < 2; ++i) {
            afh[i] = *(const h8v*)&Ah[(wm + i * 16 + lr) * 40 + lk * 8];
            afl[i] = *(const h8v*)&Al[(wm + i * 16 + lr) * 40 + lk * 8];
        }
        #pragma unroll
        for (int j = 0; j < 4; ++j) {
            bfh[j] = *(const h8v*)&Bh[(wn + j * 16 + lr) * 40 + lk * 8];
            bfl[j] = *(const h8v*)&Bl[(wn + j * 16 + lr) * 40 + lk * 8];
        }
        #pragma unroll
        for (int i = 0; i < 2; ++i)
            #pragma unroll
            for (int j = 0; j < 4; ++j) {
                acch[i][j] = __builtin_amdgcn_mfma_f32_16x16x32_f16(afh[i], bfh[j], acch[i][j], 0, 0, 0);
                accm[i][j] = __builtin_amdgcn_mfma_f32_16x16x32_f16(afh[i], bfl[j], accm[i][j], 0, 0, 0);
                accm[i][j] = __builtin_amdgcn_mfma_f32_16x16x32_f16(afl[i], bfh[j], accm[i][j], 0, 0, 0);
            }
        __syncthreads();
    }

    #pragma unroll
    for (int j = 0; j < 4; ++j) {
        int n = n0 + wn + j * 16 + lr;
        float bv = bias ? bias[n] : 0.f;
        #pragma unroll
        for (int i = 0; i < 2; ++i) {
            #pragma unroll
            for (int r = 0; r < 4; ++r) {
                int m = m0 + wm + i * 16 + lk * 4 + r;
                C[(size_t)m * N + n] = acch[i][j][r] + accm[i][j][r] * (1.0f / 2048.0f) + bv;
            }
        }
    }
}

// ---------------------------------------------------------------------------
// MFMA decoder GEMM: d1h[M,N] = (fp16)relu(A[M,K] @ B[N,K]^T + bias).
// ---------------------------------------------------------------------------
__global__ __launch_bounds__(256) void k_dgemm(
    const float* __restrict__ A, const float* __restrict__ Bm,
    const float* __restrict__ bias, half_t* __restrict__ C,
    int M, int N, int K)
{
    __shared__ __align__(16) half_t As[64 * 40];
    __shared__ __align__(16) half_t Bs[128 * 40];
    const int tid = threadIdx.x;
    const int n0 = blockIdx.x * 128, m0 = blockIdx.y * 64;
    const int w = tid >> 6, lane = tid & 63;
    const int wm = (w >> 1) * 32, wn = (w & 1) * 64;
    const int lr = lane & 15, lk = lane >> 4;

    const int ar = tid >> 2, aseg = (tid & 3) * 8;
    const int br = tid >> 1, bseg = (tid & 1) * 16;

    f4v acc[2][4];
    #pragma unroll
    for (int i = 0; i < 2; ++i)
        #pragma unroll
        for (int j = 0; j < 4; ++j) acc[i][j] = (f4v){0.f, 0.f, 0.f, 0.f};

    for (int k0 = 0; k0 < K; k0 += 32) {
        {
            const float* ap = A + (size_t)(m0 + ar) * K + k0 + aseg;
            float4 a0 = *(const float4*)ap;
            float4 a1 = *(const float4*)(ap + 4);
            h8v ha;
            ha[0] = (half_t)a0.x; ha[1] = (half_t)a0.y;
            ha[2] = (half_t)a0.z; ha[3] = (half_t)a0.w;
            ha[4] = (half_t)a1.x; ha[5] = (half_t)a1.y;
            ha[6] = (half_t)a1.z; ha[7] = (half_t)a1.w;
            *(h8v*)&As[ar * 40 + aseg] = ha;

            const float* bp = Bm + (size_t)(n0 + br) * K + k0 + bseg;
            float4 b0 = *(const float4*)bp;
            float4 b1 = *(const float4*)(bp + 4);
            float4 b2 = *(const float4*)(bp + 8);
            float4 b3 = *(const float4*)(bp + 12);
            h8v hb0, hb1;
            hb0[0] = (half_t)b0.x; hb0[1] = (half_t)b0.y;
            hb0[2] = (half_t)b0.z; hb0[3] = (half_t)b0.w;
            hb0[4] = (half_t)b1.x; hb0[5] = (half_t)b1.y;
            hb0[6] = (half_t)b1.z; hb0[7] = (half_t)b1.w;
            hb1[0] = (half_t)b2.x; hb1[1] = (half_t)b2.y;
            hb1[2] = (half_t)b2.z; hb1[3] = (half_t)b2.w;
            hb1[4] = (half_t)b3.x; hb1[5] = (half_t)b3.y;
            hb1[6] = (half_t)b3.z; hb1[7] = (half_t)b3.w;
            *(h8v*)&Bs[br * 40 + bseg] = hb0;
            *(h8v*)&Bs[br * 40 + bseg + 8] = hb1;
        }
        __syncthreads();
        h8v af[2], bfr[4];
        #pragma unroll
        for (int i = 0; i < 2; ++i)
            af[i] = *(const h8v*)&As[(wm + i * 16 + lr) * 40 + lk * 8];
        #pragma unroll
        for (int j = 0; j < 4; ++j)
            bfr[j] = *(const h8v*)&Bs[(wn + j * 16 + lr) * 40 + lk * 8];
        #pragma unroll
        for (int i = 0; i < 2; ++i)
            #pragma unroll
            for (int j = 0; j < 4; ++j)
                acc[i][j] = __builtin_amdgcn_mfma_f32_16x16x32_f16(af[i], bfr[j], acc[i][j], 0, 0, 0);
        __syncthreads();
    }

    #pragma unroll
    for (int j = 0; j < 4; ++j) {
        int n = n0 + wn + j * 16 + lr;
        float bv = bias[n];
        #pragma unroll
        for (int i = 0; i < 2; ++i) {
            #pragma unroll
            for (int r = 0; r < 4; ++r) {
                int m = m0 + wm + i * 16 + lk * 4 + r;
                C[(size_t)m * N + n] = (half_t)fmaxf(acc[i][j][r] + bv, 0.f);
            }
        }
    }
}

// ---------------------------------------------------------------------------
// Fuse dec (linear 256->3136) with convt1. Packed f2v accumulators.
// ---------------------------------------------------------------------------
__global__ __launch_bounds__(256) void k_fuse(
    const float* __restrict__ wt1, const float* __restrict__ upt1_b,
    const float* __restrict__ dec_w, const float* __restrict__ dec_b,
    float* __restrict__ Wf, float* __restrict__ bf)
{
    __shared__ float WL[4][64][32];
    const int p = blockIdx.x;
    const int k = threadIdx.x;
    const int y = p / 14, x = p % 14;

    int ky0 = 0, iy0 = 0, ky1 = 0, iy1 = 0, nky = 0;
    for (int ky = 0; ky < 4; ++ky) {
        int iyn = y + 1 - ky;
        if (iyn < 0 || (iyn & 1)) continue;
        int iy = iyn >> 1;
        if (iy > 6) continue;
        if (nky == 0) { ky0 = ky; iy0 = iy; } else { ky1 = ky; iy1 = iy; }
        ++nky;
    }
    int kx0 = 0, ix0 = 0, kx1 = 0, ix1 = 0, nkx = 0;
    for (int kx = 0; kx < 4; ++kx) {
        int ixn = x + 1 - kx;
        if (ixn < 0 || (ixn & 1)) continue;
        int ix = ixn >> 1;
        if (ix > 6) continue;
        if (nkx == 0) { kx0 = kx; ix0 = ix; } else { kx1 = kx; ix1 = ix; }
        ++nkx;
    }
    const int ntap = nky * nkx;

    for (int e = k; e < ntap * 2048; e += 256) {
        int t = e >> 11, c = (e >> 5) & 63, o = e & 31;
        int ti = (nkx == 2) ? (t >> 1) : t;
        int tj = (nkx == 2) ? (t & 1) : 0;
        int ky = ti ? ky1 : ky0;
        int kx = tj ? kx1 : kx0;
        WL[t][c][o] = wt1[((c * 32 + o) * 4 + ky) * 4 + kx];
    }
    __syncthreads();

    f2v acc2[16];
    #pragma unroll
    for (int o = 0; o < 16; ++o) acc2[o] = (f2v){0.f, 0.f};
    float bacc = 0.f;

    for (int t = 0; t < ntap; ++t) {
        int ti = (nkx == 2) ? (t >> 1) : t;
        int tj = (nkx == 2) ? (t & 1) : 0;
        int iy = ti ? iy1 : iy0;
        int ix = tj ? ix1 : ix0;
        int rbase = iy * 7 + ix;
        for (int c = 0; c < 64; ++c) {
            int row = c * 49 + rbase;
            float v = dec_w[(size_t)row * 256 + k];
            f2v vv; vv[0] = v; vv[1] = v;
            const f2v* w2p = (const f2v*)&WL[t][c][0];
            #pragma unroll
            for (int o2 = 0; o2 < 16; ++o2) acc2[o2] += vv * w2p[o2];
            if (k < 32) bacc = fmaf(WL[t][c][k], dec_b[row], bacc);
        }
    }

    #pragma unroll 4
    for (int o = 0; o < 32; ++o)
        Wf[((size_t)(p * 32 + o)) * 256 + k] = acc2[o >> 1][o & 1];
    if (k < 32) bf[p * 32 + k] = bacc + upt1_b[k];
}

// ---------------------------------------------------------------------------
// Top-k via wave __shfl_xor lexicographic (v,idx) reduce (exactly associative).
// ---------------------------------------------------------------------------
__global__ __launch_bounds__(256) void k_memread(
    const float* __restrict__ latent, const float* __restrict__ dots,
    const float* __restrict__ inv_mn, const float* __restrict__ mem,
    float* __restrict__ out)
{
    __shared__ float red[256];
    __shared__ int   redi[4];
    __shared__ float inv_x_s;
    const int b = blockIdx.x, tid = threadIdx.x;
    const int w = tid >> 6, lane = tid & 63;
    float lx = latent[(size_t)b * 256 + tid];
    red[tid] = lx * lx;
    __syncthreads();
    for (int s = 128; s > 0; s >>= 1) {
        if (tid < s) red[tid] += red[tid + s];
        __syncthreads();
    }
    if (tid == 0) inv_x_s = 1.f / fmaxf(sqrtf(red[0]), 1e-12f);
    __syncthreads();
    const float inv_x = inv_x_s;

    float vals[16];
    for (int j = 0; j < 16; ++j) {
        int m = tid + j * 256;
        vals[j] = dots[(size_t)b * 4096 + m] * inv_mn[m] * inv_x;
    }
    float tv[10]; int ti[10];
    for (int t = 0; t < 10; ++t) {
        float bv = -1e30f; int bidx = 0x7fffffff;
        #pragma unroll
        for (int j = 0; j < 16; ++j) {
            int m = tid + j * 256;
            float v = vals[j];
            if (v > bv || (v == bv && m < bidx)) { bv = v; bidx = m; }
        }
        #pragma unroll
        for (int off = 32; off > 0; off >>= 1) {
            float ov = __shfl_xor(bv, off);
            int   oi = __shfl_xor(bidx, off);
            if (ov > bv || (ov == bv && oi < bidx)) { bv = ov; bidx = oi; }
        }
        if (lane == 0) { red[w] = bv; redi[w] = bidx; }
        __syncthreads();
        float fv = red[0]; int fi = redi[0];
        #pragma unroll
        for (int q = 1; q < 4; ++q) {
            float v2 = red[q]; int i2 = redi[q];
            if (v2 > fv || (v2 == fv && i2 < fi)) { fv = v2; fi = i2; }
        }
        tv[t] = fv; ti[t] = fi;
        if ((fi & 255) == tid) vals[fi >> 8] = -1e30f;
        __syncthreads();
    }
    float wgt[10], wsum = 0.f;
    for (int t = 0; t < 10; ++t) { wgt[t] = expf(tv[t] - tv[0]); wsum += wgt[t]; }
    float inv_ws = 1.f / wsum;
    float acc = 0.f;
    for (int t = 0; t < 10; ++t) acc += (wgt[t] * inv_ws) * mem[(size_t)ti[t] * 256 + tid];
    out[(size_t)b * 256 + tid] = acc;
}

// ---------------------------------------------------------------------------
// Weight repack.
// ---------------------------------------------------------------------------
__global__ __launch_bounds__(256) void k_pack(
    const float* __restrict__ wc1, const float* __restrict__ wt2,
    const float* __restrict__ wc2, const float* __restrict__ w2src,
    half_t* __restrict__ pk2h, half_t* __restrict__ pk3h,
    float* __restrict__ pk4, float* __restrict__ pk5)
{
    int i = blockIdx.x * 256 + threadIdx.x;
    if (i < 9216) {
        int ic = i & 31, oc = (i >> 5) & 15, nt = (i >> 9) & 1, t = i >> 10;
        pk2h[i] = (half_t)wc1[((nt * 16 + oc) * 32 + ic) * 9 + t];
    }
    if (i < 8192) {
        int ic = i & 31, oc = (i >> 5) & 15, t = (i >> 9) & 3, q = i >> 11;
        int wy = t >> 1, wx = t & 1, py = q >> 1, px = q & 1;
        int ky = 3 - py - 2 * wy, kx = 3 - px - 2 * wx;
        pk3h[i] = (half_t)wt2[((ic * 16 + oc) * 4 + ky) * 4 + kx];
    }
    if (i < 1152) {
        int o = i & 7, tap = (i >> 3) % 9, c = i / 72;
        pk4[i] = wc2[(o * 16 + c) * 9 + tap];
    }
    if (i < 8192) {
        int c = i & 31, j = (i >> 5) & 127, bq = i >> 12;
        pk5[i] = w2src[bq * 4096 + c * 128 + j];
    }
}

// ---------------------------------------------------------------------------
// FUSED decoder convs: Conv2d 32->32 k3 p1 ReLU (MFMA) + ConvTranspose2d
// 32->16 k4 s2 p1 (MFMA) + Conv2d 16->8 k3 p1 ReLU + Conv2d 8->1 k1.
// One sample/block. conv1 output ReLU'd to fp16 in LDS region B (same
// quantization as the old d2h HBM round-trip -> bit-identical downstream).
// LDS: A [16][16][40]h @0 (20480) + B [16][16][40]h @20480 (20480) = 40960;
// conv2's fp32 [8][30][32] (30720) overlays A+B once both are dead.
// ---------------------------------------------------------------------------
__global__ __launch_bounds__(256) void k_c123(
    const half_t* __restrict__ in, const half_t* __restrict__ wh,
    const float* __restrict__ b1c, const half_t* __restrict__ pk3h,
    const float* __restrict__ bt2, const float* __restrict__ pk4,
    const float* __restrict__ b2, const float* __restrict__ w3,
    const float* __restrict__ b3, float* __restrict__ out)
{
    __shared__ __align__(16) unsigned char Lraw[40960];
    half_t* A  = (half_t*)Lraw;              // input d1h tile
    half_t* Bt = (half_t*)(Lraw + 20480);    // conv1 output tile
    float*  P2 = (float*)Lraw;               // conv2 group tile (overlay)
    const int tid = threadIdx.x;
    const int w = tid >> 6, lane = tid & 63;
    const int b = blockIdx.x;

    // zero both haloed tiles (10240 uints = 40960 B)
    for (int e = tid; e < 10240; e += 256) ((unsigned int*)Lraw)[e] = 0u;
    __syncthreads();
    // stage input sample channel-minor into A
    {
        const unsigned int* src = (const unsigned int*)in;
        for (int e = tid; e < 3136; e += 256) {
            int p = e >> 4, c2 = e & 15;
            int y = p / 14, x = p % 14;
            ((unsigned int*)A)[((y + 1) * 16 + (x + 1)) * 20 + c2] =
                src[(size_t)b * 3136 + e];
        }
    }

    const int oc = lane & 15;
    const int kseg = (lane >> 4) * 8;

    // preload conv1 B-frags (MFMA B layout)
    h8v bfr1[9][2];
    #pragma unroll
    for (int t = 0; t < 9; ++t)
        #pragma unroll
        for (int nt = 0; nt < 2; ++nt)
            bfr1[t][nt] = *(const h8v*)&wh[((size_t)((t * 2 + nt) * 16 + oc)) * 32 + kseg];

    __syncthreads();   // staging visible

    // ---- conv1 (MFMA): 13 tiles, results ReLU'd fp16 -> region B ----
    {
        const float bv0 = b1c[oc], bv1 = b1c[16 + oc];
        for (int tile = w; tile < 13; tile += 4) {
            int p = tile * 16 + (lane & 15);
            if (p > 195) p = 195;
            const int y = p / 14, x = p % 14;
            f4v acc0 = (f4v){0.f, 0.f, 0.f, 0.f};
            f4v acc1 = (f4v){0.f, 0.f, 0.f, 0.f};
            #pragma unroll
            for (int ky = 0; ky < 3; ++ky) {
                #pragma unroll
                for (int kx = 0; kx < 3; ++kx) {
                    h8v af = *(const h8v*)&A[((y + ky) * 16 + (x + kx)) * 40 + kseg];
                    acc0 = __builtin_amdgcn_mfma_f32_16x16x32_f16(af, bfr1[ky * 3 + kx][0], acc0, 0, 0, 0);
                    acc1 = __builtin_amdgcn_mfma_f32_16x16x32_f16(af, bfr1[ky * 3 + kx][1], acc1, 0, 0, 0);
                }
            }
            const int pr0 = tile * 16 + (lane >> 4) * 4;
            #pragma unroll
            for (int r = 0; r < 4; ++r) {
                int pp = pr0 + r;
                if (pp < 196) {
                    int yy = pp / 14, xx = pp % 14;
                    int base = ((yy + 1) * 16 + (xx + 1)) * 40;
                    Bt[base + oc]      = (half_t)fmaxf(acc0[r] + bv0, 0.f);
                    Bt[base + 16 + oc] = (half_t)fmaxf(acc1[r] + bv1, 0.f);
                }
            }
        }
    }
    __syncthreads();   // conv1 output visible; A now dead

    // ---- convt2 (MFMA): 52 jobs, results in registers ----
    f4v res[13];
    #pragma unroll
    for (int j = 0; j < 13; ++j) {
        const int job = w + 4 * j;
        const int q = job / 13, tile = job - q * 13;
        const int py = q >> 1, px = q & 1;
        int p = tile * 16 + (lane & 15);
        if (p > 195) p = 195;
        const int ty = p / 14, tx = p % 14;
        f4v a = (f4v){0.f, 0.f, 0.f, 0.f};
        #pragma unroll
        for (int t = 0; t < 4; ++t) {
            const int wy = t >> 1, wx = t & 1;
            h8v bf = *(const h8v*)&pk3h[((size_t)((q * 4 + t) * 16 + oc)) * 32 + kseg];
            h8v af = *(const h8v*)&Bt[((ty + py + wy) * 16 + (tx + px + wx)) * 40 + kseg];
            a = __builtin_amdgcn_mfma_f32_16x16x32_f16(af, bf, a, 0, 0, 0);
        }
        res[j] = a;
    }
    __syncthreads();   // all B reads done; P2 overlay safe

    // ---- conv2 (16->8, k3, ReLU; packed f2v) + conv3 (8->1) ----
    const bool active2 = tid < 196;
    int row = active2 ? tid / 7 : 0;
    int tx0b = active2 ? (tid % 7) * 4 : 0;
    const float bco = bt2[oc];

    f2v acc2[4][4];
    #pragma unroll
    for (int i = 0; i < 4; ++i)
        #pragma unroll
        for (int o2 = 0; o2 < 4; ++o2) acc2[i][o2] = (f2v){0.f, 0.f};

    #pragma unroll
    for (int g = 0; g < 2; ++g) {
        for (int e = tid; e < 7680; e += 256) P2[e] = 0.f;
        __syncthreads();
        if ((oc >> 3) == g) {
            #pragma unroll
            for (int j = 0; j < 13; ++j) {
                const int job = w + 4 * j;
                const int q = job / 13, tile = job - q * 13;
                const int py = q >> 1, px = q & 1;
                const int pr0 = tile * 16 + (lane >> 4) * 4;
                #pragma unroll
                for (int r = 0; r < 4; ++r) {
                    int p = pr0 + r;
                    if (p < 196) {
                        int Y = 2 * (p / 14) + py, X = 2 * (p % 14) + px;
                        P2[((oc & 7) * 30 + Y + 1) * 32 + (X + 1)] = fmaxf(res[j][r] + bco, 0.f);
                    }
                }
            }
        }
        __syncthreads();
        for (int cl = 0; cl < 8; ++cl) {
            const float* Pb = &P2[(cl * 30 + row) * 32 + tx0b];
            const float* wb = pk4 + (size_t)(g * 8 + cl) * 72;
            #pragma unroll
            for (int ky = 0; ky < 3; ++ky) {
                float4 a = *(const float4*)&Pb[ky * 32];
                float4 bq = *(const float4*)&Pb[ky * 32 + 4];
                float rowb[8] = {a.x, a.y, a.z, a.w, bq.x, bq.y, bq.z, bq.w};
                #pragma unroll
                for (int kx = 0; kx < 3; ++kx) {
                    const f2v* wt2p = (const f2v*)(wb + (ky * 3 + kx) * 8);
                    #pragma unroll
                    for (int i = 0; i < 4; ++i) {
                        f2v rb; rb[0] = rowb[i + kx]; rb[1] = rowb[i + kx];
                        acc2[i][0] += rb * wt2p[0];
                        acc2[i][1] += rb * wt2p[1];
                        acc2[i][2] += rb * wt2p[2];
                        acc2[i][3] += rb * wt2p[3];
                    }
                }
            }
        }
        __syncthreads();
    }

    if (active2) {
        const float bias3 = b3[0];
        #pragma unroll
        for (int i = 0; i < 4; ++i) {
            float r = bias3;
            #pragma unroll
            for (int o = 0; o < 8; ++o)
                r += fmaxf(acc2[i][o >> 1][o & 1] + b2[o], 0.f) * w3[o];
            out[(size_t)b * 784 + row * 28 + tx0b + i] = r;
        }
    }
}

// ---------------------------------------------------------------------------
extern "C" void kernel_launch(void* const* d_in, const int* in_sizes, int n_in,
                              void* d_out, int out_size, void* d_ws, size_t ws_size,
                              hipStream_t stream)
{
    const float* x       = (const float*)d_in[0];
    const float* patch_w = (const float*)d_in[1];
    const float* patch_b = (const float*)d_in[2];
    const float* ln1g    = (const float*)d_in[3];
    const float* ln1b    = (const float*)d_in[4];
    const float* wi      = (const float*)d_in[5];
    const float* bi      = (const float*)d_in[6];
    const float* wo      = (const float*)d_in[7];
    const float* bo      = (const float*)d_in[8];
    const float* ln2g    = (const float*)d_in[9];
    const float* ln2b    = (const float*)d_in[10];
    const float* w1      = (const float*)d_in[11];
    const float* b1      = (const float*)d_in[12];
    const float* w2      = (const float*)d_in[13];
    const float* b2      = (const float*)d_in[14];
    const float* lat_w   = (const float*)d_in[15];
    const float* lat_b   = (const float*)d_in[16];
    const float* memory  = (const float*)d_in[17];
    const float* dec_w   = (const float*)d_in[18];
    const float* dec_b   = (const float*)d_in[19];
    const float* upt1_w  = (const float*)d_in[20];
    const float* upt1_b  = (const float*)d_in[21];
    const float* c1_w    = (const float*)d_in[22];
    const float* c1_b    = (const float*)d_in[23];
    const float* upt2_w  = (const float*)d_in[24];
    const float* upt2_b  = (const float*)d_in[25];
    const float* c2_w    = (const float*)d_in[26];
    const float* c2_b    = (const float*)d_in[27];
    const float* c3_w    = (const float*)d_in[28];
    const float* c3_b    = (const float*)d_in[29];
    float* outp = (float*)d_out;

    float* ws = (float*)d_ws;
    size_t off = 0;
    auto alloc = [&](size_t n) { float* p = ws + off; off += (n + 63) & ~(size_t)63; return p; };
    float* tokens     = alloc((size_t)B_TOT * 1568);
    float* latent     = alloc((size_t)B_TOT * 256);
    float* dots       = alloc((size_t)B_TOT * 4096);
    float* mem_latent = alloc((size_t)B_TOT * 256);
    float* inv_mn     = alloc(4096);
    half_t* pk2h      = (half_t*)alloc(4608);
    half_t* pk3h      = (half_t*)alloc(4096);
    float* pk4        = alloc(1152);
    float* pk5        = alloc(8192);
    float* Wf         = alloc((size_t)6272 * 256);
    float* bf         = alloc(6272);
    half_t* d1h       = (half_t*)alloc((size_t)CHUNK * 6272 / 2);
    half_t* lwh       = (half_t*)alloc(200704);   // 256*1568 halves
    half_t* lwl       = (half_t*)alloc(200704);
    half_t* memh      = (half_t*)alloc(524288);   // 4096*256 halves
    half_t* meml      = (half_t*)alloc(524288);
    (void)in_sizes; (void)n_in; (void)out_size; (void)ws_size;

    // Prep: repack, pre-split GEMM B operands (+inv_norm), dec/convt1 fusion
    k_pack<<<36, 256, 0, stream>>>(c1_w, upt2_w, c2_w, w2, pk2h, pk3h, pk4, pk5);
    k_split<<<4096, 256, 0, stream>>>(lat_w, memory, lwh, lwl, memh, meml, inv_mn);
    k_fuse<<<196, 256, 0, stream>>>(upt1_w, upt1_b, dec_w, dec_b, Wf, bf);

    // Encoder (wave-per-sample, packed fp32 math)
    k_tokens<<<B_TOT / 4, 256, 0, stream>>>(x, patch_w, patch_b, ln1g, ln1b, wi, bi,
                                            wo, bo, ln2g, ln2b, w1, b1, pk5, b2, tokens);
    // latent + dots via split-fp16 MFMA with pre-split B
    k_sgemm<<<dim3(256 / 128, B_TOT / 64), 256, 0, stream>>>(tokens, lwh, lwl, lat_b,
                                                             latent, B_TOT, 256, 1568);
    k_sgemm<<<dim3(4096 / 128, B_TOT / 64), 256, 0, stream>>>(latent, memh, meml, nullptr,
                                                              dots, B_TOT, 4096, 256);
    k_memread<<<B_TOT, 256, 0, stream>>>(latent, dots, inv_mn, memory, mem_latent);

    // Decoder: MFMA GEMM -> d1h; fused conv1+convt2+conv2+conv3 -> output.
    for (int c = 0; c < B_TOT / CHUNK; ++c) {
        const float* ml = mem_latent + (size_t)c * CHUNK * 256;
        k_dgemm<<<dim3(6272 / 128, CHUNK / 64), 256, 0, stream>>>(ml, Wf, bf, d1h,
                                                                  CHUNK, 6272, 256);
        k_c123<<<CHUNK, 256, 0, stream>>>(d1h, pk2h, c1_b, pk3h, upt2_b, pk4,
                                          c2_b, c3_w, c3_b,
                                          outp + (size_t)c * CHUNK * 784);
    }
}